// Round 3
// baseline (909.664 us; speedup 1.0000x reference)
//
#include <hip/hip_runtime.h>

#define NN 100000
#define NE 1600000
#define W_BKT 128
#define NB_BKT ((NN + W_BKT - 1) / W_BKT)   // 782
// IN=128, HID=64, OUT=32

// ---------------- degree / CSR build ----------------

__global__ __launch_bounds__(256) void k_hist(const int* __restrict__ dst, int* __restrict__ hist) {
    int e = blockIdx.x * 256 + threadIdx.x;
    if (e < NE) atomicAdd(&hist[dst[e]], 1);
}

__global__ __launch_bounds__(256) void k_dis(const int* __restrict__ hist, float* __restrict__ dis) {
    int i = blockIdx.x * 256 + threadIdx.x;
    if (i < NN) dis[i] = rsqrtf((float)(1 + hist[i]));   // +1 self-loop
}

// per-block exclusive scan of hist -> row_ptr(local), block total -> partial[b]
__global__ __launch_bounds__(256) void k_scan1(const int* __restrict__ hist,
                                               int* __restrict__ row_ptr,
                                               int* __restrict__ partial) {
    __shared__ int buf[256];
    int tid = threadIdx.x;
    int i = blockIdx.x * 256 + tid;
    int v = (i < NN) ? hist[i] : 0;
    buf[tid] = v;
    __syncthreads();
    for (int off = 1; off < 256; off <<= 1) {
        int t = (tid >= off) ? buf[tid - off] : 0;
        __syncthreads();
        buf[tid] += t;
        __syncthreads();
    }
    if (i < NN) row_ptr[i] = buf[tid] - v;     // exclusive within block
    if (tid == 255) partial[blockIdx.x] = buf[255];
}

// exclusive scan of 391 block partials (one block of 512)
__global__ __launch_bounds__(512) void k_scan2(int* __restrict__ partial, int nb) {
    __shared__ int buf[512];
    int tid = threadIdx.x;
    int v = (tid < nb) ? partial[tid] : 0;
    buf[tid] = v;
    __syncthreads();
    for (int off = 1; off < 512; off <<= 1) {
        int t = (tid >= off) ? buf[tid - off] : 0;
        __syncthreads();
        buf[tid] += t;
        __syncthreads();
    }
    partial[tid] = buf[tid] - v;   // exclusive
}

// add block offsets; write row_ptr[NN]
__global__ __launch_bounds__(256) void k_scan3(int* __restrict__ row_ptr,
                                               const int* __restrict__ partial) {
    int i = blockIdx.x * 256 + threadIdx.x;
    if (i < NN) row_ptr[i] += partial[blockIdx.x];
    if (i == 0) row_ptr[NN] = NE;
}

// bucket cursors = final CSR offsets of each bucket's first node
__global__ __launch_bounds__(256) void k_bcur(const int* __restrict__ row_ptr,
                                              int* __restrict__ bcur) {
    int b = blockIdx.x * 256 + threadIdx.x;
    if (b < NB_BKT) bcur[b] = row_ptr[b * W_BKT];
}

// pass A: scatter packed (src<<7 | d&127) into bucket-ordered ebuf.
// active write frontier = 782 lines (~50 KB) -> L2-resident, no thrash.
__global__ __launch_bounds__(256) void k_fill_a(const int* __restrict__ src,
                                                const int* __restrict__ dst,
                                                int* __restrict__ bcur,
                                                int* __restrict__ ebuf) {
    int e = blockIdx.x * 256 + threadIdx.x;
    if (e >= NE) return;
    int s = src[e], d = dst[e];
    int pos = atomicAdd(&bcur[d >> 7], 1);
    ebuf[pos] = (s << 7) | (d & 127);
}

// pass B: one block per bucket; per-node cursors in LDS; contiguous-region writes.
__global__ __launch_bounds__(256) void k_fill_b(const int* __restrict__ row_ptr,
                                                const int* __restrict__ ebuf,
                                                int* __restrict__ csr_src) {
    __shared__ int cur[W_BKT];
    int b = blockIdx.x;
    int v0 = b * W_BKT;
    int tid = threadIdx.x;
    if (tid < W_BKT) {
        int v = v0 + tid;
        cur[tid] = (v < NN) ? row_ptr[v] : NE;
    }
    int vend = v0 + W_BKT; if (vend > NN) vend = NN;
    int beg = row_ptr[v0];
    int end = row_ptr[vend];
    __syncthreads();
    for (int i = beg + tid; i < end; i += 256) {
        int val = ebuf[i];
        int pos = atomicAdd(&cur[val & 127], 1);
        csr_src[pos] = val >> 7;
    }
}

// ---------------- dense transforms ----------------

// t1[N,64] = x[N,128] @ W1[128,64].  16 rows per block, W1 + x-tile in LDS.
__global__ __launch_bounds__(256) void k_gemm1(const float* __restrict__ x,
                                               const float* __restrict__ W1,
                                               float* __restrict__ t1) {
    __shared__ float Wl[128 * 64];
    __shared__ float Xl[16 * 128];
    int tid = threadIdx.x;
    const float4* W4 = (const float4*)W1;
    float4* Wl4 = (float4*)Wl;
    for (int i = tid; i < 128 * 16; i += 256) Wl4[i] = W4[i];
    long rowbase = (long)blockIdx.x * 16;      // N = 6250 * 16 exactly
    const float4* X4 = (const float4*)(x + rowbase * 128);
    float4* Xl4 = (float4*)Xl;
    for (int i = tid; i < 16 * 32; i += 256) Xl4[i] = X4[i];
    __syncthreads();
    int col = tid & 63, rg = tid >> 6;
    float acc[4] = {0.f, 0.f, 0.f, 0.f};
    for (int k = 0; k < 128; ++k) {
        float w = Wl[k * 64 + col];
#pragma unroll
        for (int i = 0; i < 4; ++i) acc[i] += Xl[(rg * 4 + i) * 128 + k] * w;
    }
#pragma unroll
    for (int i = 0; i < 4; ++i)
        t1[(rowbase + rg * 4 + i) * 64 + col] = acc[i];
}

// t2[N,64] = h[N,64] @ [Wmu | Wls]  (each [64,32])
__global__ __launch_bounds__(256) void k_gemm2(const float* __restrict__ h,
                                               const float* __restrict__ Wmu,
                                               const float* __restrict__ Wls,
                                               float* __restrict__ t2) {
    __shared__ float Wl[64 * 64];
    __shared__ float Hl[16 * 64];
    int tid = threadIdx.x;
    for (int i = tid; i < 64 * 64; i += 256) {
        int k = i >> 6, j = i & 63;
        Wl[i] = (j < 32) ? Wmu[k * 32 + j] : Wls[k * 32 + j - 32];
    }
    long rowbase = (long)blockIdx.x * 16;
    const float4* H4 = (const float4*)(h + rowbase * 64);
    float4* Hl4 = (float4*)Hl;
    for (int i = tid; i < 16 * 16; i += 256) Hl4[i] = H4[i];
    __syncthreads();
    int col = tid & 63, rg = tid >> 6;
    float acc[4] = {0.f, 0.f, 0.f, 0.f};
    for (int k = 0; k < 64; ++k) {
        float w = Wl[k * 64 + col];
#pragma unroll
        for (int i = 0; i < 4; ++i) acc[i] += Hl[(rg * 4 + i) * 64 + k] * w;
    }
#pragma unroll
    for (int i = 0; i < 4; ++i)
        t2[(rowbase + rg * 4 + i) * 64 + col] = acc[i];
}

// ---------------- fused gather-aggregations ----------------

// h[v] = l2normalize(relu(dis[v]*(sum_s dis[s]*t1[s] + dis[v]*t1[v]) + b1))
__global__ __launch_bounds__(256) void k_agg1(const float* __restrict__ t1,
                                              const int* __restrict__ row_ptr,
                                              const int* __restrict__ csr_src,
                                              const float* __restrict__ dis,
                                              const float* __restrict__ b1,
                                              float* __restrict__ h) {
    long t = (long)blockIdx.x * 256 + threadIdx.x;
    int v = (int)(t >> 6), j = (int)(t & 63);
    if (v >= NN) return;
    int beg = row_ptr[v], end = row_ptr[v + 1];
    float acc = 0.f;
    int i = beg;
    for (; i + 4 <= end; i += 4) {
        int s0 = csr_src[i], s1 = csr_src[i + 1], s2 = csr_src[i + 2], s3 = csr_src[i + 3];
        float a0 = dis[s0] * t1[s0 * 64 + j];
        float a1 = dis[s1] * t1[s1 * 64 + j];
        float a2 = dis[s2] * t1[s2 * 64 + j];
        float a3 = dis[s3] * t1[s3 * 64 + j];
        acc += (a0 + a1) + (a2 + a3);
    }
    for (; i < end; ++i) {
        int s = csr_src[i];
        acc += dis[s] * t1[s * 64 + j];
    }
    float dv = dis[v];
    float val = dv * (acc + dv * t1[v * 64 + j]) + b1[j];
    val = fmaxf(val, 0.0f);
    float ss = val * val;
#pragma unroll
    for (int m = 1; m < 64; m <<= 1) ss += __shfl_xor(ss, m);
    float scale = 1.0f / fmaxf(sqrtf(ss), 1e-12f);
    h[v * 64 + j] = val * scale;
}

// layer-2 aggregation fused with bias + reparametrize; writes mu, ls, z
__global__ __launch_bounds__(256) void k_agg2(const float* __restrict__ t2,
                                              const int* __restrict__ row_ptr,
                                              const int* __restrict__ csr_src,
                                              const float* __restrict__ dis,
                                              const float* __restrict__ bmu,
                                              const float* __restrict__ bls,
                                              const float* __restrict__ eps,
                                              float* __restrict__ mu,
                                              float* __restrict__ ls,
                                              float* __restrict__ z) {
    long t = (long)blockIdx.x * 256 + threadIdx.x;
    int v = (int)(t >> 6), j = (int)(t & 63);
    if (v >= NN) return;
    int beg = row_ptr[v], end = row_ptr[v + 1];
    float acc = 0.f;
    int i = beg;
    for (; i + 4 <= end; i += 4) {
        int s0 = csr_src[i], s1 = csr_src[i + 1], s2 = csr_src[i + 2], s3 = csr_src[i + 3];
        float a0 = dis[s0] * t2[s0 * 64 + j];
        float a1 = dis[s1] * t2[s1 * 64 + j];
        float a2 = dis[s2] * t2[s2 * 64 + j];
        float a3 = dis[s3] * t2[s3 * 64 + j];
        acc += (a0 + a1) + (a2 + a3);
    }
    for (; i < end; ++i) {
        int s = csr_src[i];
        acc += dis[s] * t2[s * 64 + j];
    }
    float dv = dis[v];
    float val = dv * (acc + dv * t2[v * 64 + j]) + ((j < 32) ? bmu[j] : bls[j - 32]);
    float other = __shfl_xor(val, 32);
    if (j < 32) {
        mu[v * 32 + j] = val;
        float lc = fminf(fmaxf(other, -10.0f), 10.0f);
        z[v * 32 + j] = val + eps[v * 32 + j] * expf(lc);
    } else {
        ls[v * 32 + j - 32] = val;
    }
}

// adj_pred[e] = sigmoid(<z[src], z[dst]>), 8 lanes per edge, float4 loads
__global__ __launch_bounds__(256) void k_decode(const float* __restrict__ z,
                                                const int* __restrict__ src,
                                                const int* __restrict__ dst,
                                                float* __restrict__ out) {
    long t = (long)blockIdx.x * 256 + threadIdx.x;
    long e = t >> 3; int l = (int)(t & 7);
    if (e >= NE) return;
    int s = src[e], d = dst[e];
    const float4* z4 = (const float4*)z;
    float4 a = z4[s * 8 + l];
    float4 b = z4[d * 8 + l];
    float p = a.x * b.x + a.y * b.y + a.z * b.z + a.w * b.w;
    p += __shfl_xor(p, 1);
    p += __shfl_xor(p, 2);
    p += __shfl_xor(p, 4);
    if (l == 0) out[e] = 1.0f / (1.0f + expf(-p));
}

extern "C" void kernel_launch(void* const* d_in, const int* in_sizes, int n_in,
                              void* d_out, int out_size, void* d_ws, size_t ws_size,
                              hipStream_t stream) {
    const float* x   = (const float*)d_in[0];
    const int*   ei  = (const int*)d_in[1];
    const float* eps = (const float*)d_in[2];
    const float* W1  = (const float*)d_in[3];
    const float* b1  = (const float*)d_in[4];
    const float* Wmu = (const float*)d_in[5];
    const float* bmu = (const float*)d_in[6];
    const float* Wls = (const float*)d_in[7];
    const float* bls = (const float*)d_in[8];
    const int* src = ei;        // edge_index[0]
    const int* dst = ei + NE;   // edge_index[1]

    float* out = (float*)d_out;
    float* adj = out;                       // [E]
    float* mu  = out + NE;                  // [N,32]
    float* ls  = mu + (long)NN * 32;        // [N,32]

    // workspace layout (all block sizes multiples of 4 elements -> 16B aligned)
    float* dis     = (float*)d_ws;              // NN
    int*   row_ptr = (int*)(dis + NN);          // 100004
    int*   hist    = row_ptr + 100004;          // NN
    int*   partial = hist + NN;                 // 512
    int*   bcur    = partial + 512;             // 784
    int*   ebuf    = bcur + 784;                // NE
    int*   csr_src = ebuf + NE;                 // NE
    float* t       = (float*)(csr_src + NE);    // NN*64  (t1 then t2)
    float* h       = t + (long)NN * 64;         // NN*64
    float* z       = h + (long)NN * 64;         // NN*32

    const int B = 256;
    const int NB_N = (NN + B - 1) / B;          // 391
    const int NB_E = (NE + B - 1) / B;          // 6250

    hipMemsetAsync(hist, 0, (size_t)NN * sizeof(int), stream);

    // CSR build + dis
    k_hist  <<<NB_E, B, 0, stream>>>(dst, hist);
    k_dis   <<<NB_N, B, 0, stream>>>(hist, dis);
    k_scan1 <<<NB_N, B, 0, stream>>>(hist, row_ptr, partial);
    k_scan2 <<<1, 512, 0, stream>>>(partial, NB_N);
    k_scan3 <<<NB_N, B, 0, stream>>>(row_ptr, partial);
    k_bcur  <<<(NB_BKT + B - 1) / B, B, 0, stream>>>(row_ptr, bcur);
    k_fill_a<<<NB_E, B, 0, stream>>>(src, dst, bcur, ebuf);
    k_fill_b<<<NB_BKT, B, 0, stream>>>(row_ptr, ebuf, csr_src);

    // layer 1
    k_gemm1<<<NN / 16, B, 0, stream>>>(x, W1, t);
    k_agg1 <<<(int)(((long)NN * 64 + B - 1) / B), B, 0, stream>>>(t, row_ptr, csr_src, dis, b1, h);

    // layer 2
    k_gemm2<<<NN / 16, B, 0, stream>>>(h, Wmu, Wls, t);
    k_agg2 <<<(int)(((long)NN * 64 + B - 1) / B), B, 0, stream>>>(t, row_ptr, csr_src, dis,
                                                                  bmu, bls, eps, mu, ls, z);

    // decode
    k_decode<<<(int)(((long)NE * 8 + B - 1) / B), B, 0, stream>>>(z, src, dst, adj);
}

// Round 4
// 586.659 us; speedup vs baseline: 1.5506x; 1.5506x over previous
//
#include <hip/hip_runtime.h>

#define NN 100000
#define NE 1600000
#define W_BKT 128
#define NB_BKT ((NN + W_BKT - 1) / W_BKT)   // 782
#define TILE_E 16384                         // edges per counting-sort tile
#define NT ((NE + TILE_E - 1) / TILE_E)      // 98
// IN=128, HID=64, OUT=32

// ---------------- degree / CSR build ----------------

__global__ __launch_bounds__(256) void k_hist(const int* __restrict__ dst, int* __restrict__ hist) {
    int e = blockIdx.x * 256 + threadIdx.x;
    if (e < NE) atomicAdd(&hist[dst[e]], 1);
}

__global__ __launch_bounds__(256) void k_dis(const int* __restrict__ hist, float* __restrict__ dis) {
    int i = blockIdx.x * 256 + threadIdx.x;
    if (i < NN) dis[i] = rsqrtf((float)(1 + hist[i]));   // +1 self-loop
}

// per-block exclusive scan of hist -> row_ptr(local), block total -> partial[b]
__global__ __launch_bounds__(256) void k_scan1(const int* __restrict__ hist,
                                               int* __restrict__ row_ptr,
                                               int* __restrict__ partial) {
    __shared__ int buf[256];
    int tid = threadIdx.x;
    int i = blockIdx.x * 256 + tid;
    int v = (i < NN) ? hist[i] : 0;
    buf[tid] = v;
    __syncthreads();
    for (int off = 1; off < 256; off <<= 1) {
        int t = (tid >= off) ? buf[tid - off] : 0;
        __syncthreads();
        buf[tid] += t;
        __syncthreads();
    }
    if (i < NN) row_ptr[i] = buf[tid] - v;     // exclusive within block
    if (tid == 255) partial[blockIdx.x] = buf[255];
}

// exclusive scan of 391 block partials (one block of 512)
__global__ __launch_bounds__(512) void k_scan2(int* __restrict__ partial, int nb) {
    __shared__ int buf[512];
    int tid = threadIdx.x;
    int v = (tid < nb) ? partial[tid] : 0;
    buf[tid] = v;
    __syncthreads();
    for (int off = 1; off < 512; off <<= 1) {
        int t = (tid >= off) ? buf[tid - off] : 0;
        __syncthreads();
        buf[tid] += t;
        __syncthreads();
    }
    partial[tid] = buf[tid] - v;   // exclusive
}

// add block offsets; write row_ptr[NN]
__global__ __launch_bounds__(256) void k_scan3(int* __restrict__ row_ptr,
                                               const int* __restrict__ partial) {
    int i = blockIdx.x * 256 + threadIdx.x;
    if (i < NN) row_ptr[i] += partial[blockIdx.x];
    if (i == 0) row_ptr[NN] = NE;
}

// ---- deterministic two-pass bucket sort (NO global atomics) ----

// per-tile bucket histogram via LDS atomics
__global__ __launch_bounds__(256) void k_cnt(const int* __restrict__ dst,
                                             int* __restrict__ counts) {
    __shared__ int hc[NB_BKT];
    int tid = threadIdx.x;
    for (int i = tid; i < NB_BKT; i += 256) hc[i] = 0;
    __syncthreads();
    int base = blockIdx.x * TILE_E;
    int lim = base + TILE_E; if (lim > NE) lim = NE;
    for (int e = base + tid; e < lim; e += 256)
        atomicAdd(&hc[dst[e] >> 7], 1);
    __syncthreads();
    for (int i = tid; i < NB_BKT; i += 256)
        counts[blockIdx.x * NB_BKT + i] = hc[i];
}

// thread per bucket: running sum over tiles, seeded from row_ptr -> base offsets
__global__ __launch_bounds__(256) void k_offs(const int* __restrict__ row_ptr,
                                              int* __restrict__ counts) {
    int b = blockIdx.x * 256 + threadIdx.x;
    if (b >= NB_BKT) return;
    int off = row_ptr[b * W_BKT];
    for (int t = 0; t < NT; ++t) {
        int c = counts[t * NB_BKT + b];
        counts[t * NB_BKT + b] = off;
        off += c;
    }
}

// re-read tile, place packed (src<<7 | d&127) at deterministic positions
__global__ __launch_bounds__(256) void k_place(const int* __restrict__ src,
                                               const int* __restrict__ dst,
                                               const int* __restrict__ counts,
                                               int* __restrict__ ebuf) {
    __shared__ int cur[NB_BKT];
    int tid = threadIdx.x;
    for (int i = tid; i < NB_BKT; i += 256)
        cur[i] = counts[blockIdx.x * NB_BKT + i];
    __syncthreads();
    int base = blockIdx.x * TILE_E;
    int lim = base + TILE_E; if (lim > NE) lim = NE;
    for (int e = base + tid; e < lim; e += 256) {
        int s = src[e], d = dst[e];
        int pos = atomicAdd(&cur[d >> 7], 1);     // LDS atomic, ~21/counter
        ebuf[pos] = (s << 7) | (d & 127);
    }
}

// pass B: one block per bucket; per-node cursors in LDS; contiguous-region writes.
__global__ __launch_bounds__(256) void k_fill_b(const int* __restrict__ row_ptr,
                                                const int* __restrict__ ebuf,
                                                int* __restrict__ csr_src) {
    __shared__ int cur[W_BKT];
    int b = blockIdx.x;
    int v0 = b * W_BKT;
    int tid = threadIdx.x;
    if (tid < W_BKT) {
        int v = v0 + tid;
        cur[tid] = (v < NN) ? row_ptr[v] : NE;
    }
    int vend = v0 + W_BKT; if (vend > NN) vend = NN;
    int beg = row_ptr[v0];
    int end = row_ptr[vend];
    __syncthreads();
    for (int i = beg + tid; i < end; i += 256) {
        int val = ebuf[i];
        int pos = atomicAdd(&cur[val & 127], 1);
        csr_src[pos] = val >> 7;
    }
}

// ---------------- dense transforms ----------------

// t1[N,64] = x[N,128] @ W1[128,64].  16 rows per block, W1 + x-tile in LDS.
__global__ __launch_bounds__(256) void k_gemm1(const float* __restrict__ x,
                                               const float* __restrict__ W1,
                                               float* __restrict__ t1) {
    __shared__ float Wl[128 * 64];
    __shared__ float Xl[16 * 128];
    int tid = threadIdx.x;
    const float4* W4 = (const float4*)W1;
    float4* Wl4 = (float4*)Wl;
    for (int i = tid; i < 128 * 16; i += 256) Wl4[i] = W4[i];
    long rowbase = (long)blockIdx.x * 16;      // N = 6250 * 16 exactly
    const float4* X4 = (const float4*)(x + rowbase * 128);
    float4* Xl4 = (float4*)Xl;
    for (int i = tid; i < 16 * 32; i += 256) Xl4[i] = X4[i];
    __syncthreads();
    int col = tid & 63, rg = tid >> 6;
    float acc[4] = {0.f, 0.f, 0.f, 0.f};
    for (int k = 0; k < 128; ++k) {
        float w = Wl[k * 64 + col];
#pragma unroll
        for (int i = 0; i < 4; ++i) acc[i] += Xl[(rg * 4 + i) * 128 + k] * w;
    }
#pragma unroll
    for (int i = 0; i < 4; ++i)
        t1[(rowbase + rg * 4 + i) * 64 + col] = acc[i];
}

// t2[N,64] = h[N,64] @ [Wmu | Wls]  (each [64,32])
__global__ __launch_bounds__(256) void k_gemm2(const float* __restrict__ h,
                                               const float* __restrict__ Wmu,
                                               const float* __restrict__ Wls,
                                               float* __restrict__ t2) {
    __shared__ float Wl[64 * 64];
    __shared__ float Hl[16 * 64];
    int tid = threadIdx.x;
    for (int i = tid; i < 64 * 64; i += 256) {
        int k = i >> 6, j = i & 63;
        Wl[i] = (j < 32) ? Wmu[k * 32 + j] : Wls[k * 32 + j - 32];
    }
    long rowbase = (long)blockIdx.x * 16;
    const float4* H4 = (const float4*)(h + rowbase * 64);
    float4* Hl4 = (float4*)Hl;
    for (int i = tid; i < 16 * 16; i += 256) Hl4[i] = H4[i];
    __syncthreads();
    int col = tid & 63, rg = tid >> 6;
    float acc[4] = {0.f, 0.f, 0.f, 0.f};
    for (int k = 0; k < 64; ++k) {
        float w = Wl[k * 64 + col];
#pragma unroll
        for (int i = 0; i < 4; ++i) acc[i] += Hl[(rg * 4 + i) * 64 + k] * w;
    }
#pragma unroll
    for (int i = 0; i < 4; ++i)
        t2[(rowbase + rg * 4 + i) * 64 + col] = acc[i];
}

// ---------------- fused gather-aggregations ----------------

// h[v] = l2normalize(relu(dis[v]*(sum_s dis[s]*t1[s] + dis[v]*t1[v]) + b1))
__global__ __launch_bounds__(256) void k_agg1(const float* __restrict__ t1,
                                              const int* __restrict__ row_ptr,
                                              const int* __restrict__ csr_src,
                                              const float* __restrict__ dis,
                                              const float* __restrict__ b1,
                                              float* __restrict__ h) {
    long t = (long)blockIdx.x * 256 + threadIdx.x;
    int v = (int)(t >> 6), j = (int)(t & 63);
    if (v >= NN) return;
    int beg = row_ptr[v], end = row_ptr[v + 1];
    float acc = 0.f;
    int i = beg;
    for (; i + 4 <= end; i += 4) {
        int s0 = csr_src[i], s1 = csr_src[i + 1], s2 = csr_src[i + 2], s3 = csr_src[i + 3];
        float a0 = dis[s0] * t1[s0 * 64 + j];
        float a1 = dis[s1] * t1[s1 * 64 + j];
        float a2 = dis[s2] * t1[s2 * 64 + j];
        float a3 = dis[s3] * t1[s3 * 64 + j];
        acc += (a0 + a1) + (a2 + a3);
    }
    for (; i < end; ++i) {
        int s = csr_src[i];
        acc += dis[s] * t1[s * 64 + j];
    }
    float dv = dis[v];
    float val = dv * (acc + dv * t1[v * 64 + j]) + b1[j];
    val = fmaxf(val, 0.0f);
    float ss = val * val;
#pragma unroll
    for (int m = 1; m < 64; m <<= 1) ss += __shfl_xor(ss, m);
    float scale = 1.0f / fmaxf(sqrtf(ss), 1e-12f);
    h[v * 64 + j] = val * scale;
}

// layer-2 aggregation fused with bias + reparametrize; writes mu, ls, z
__global__ __launch_bounds__(256) void k_agg2(const float* __restrict__ t2,
                                              const int* __restrict__ row_ptr,
                                              const int* __restrict__ csr_src,
                                              const float* __restrict__ dis,
                                              const float* __restrict__ bmu,
                                              const float* __restrict__ bls,
                                              const float* __restrict__ eps,
                                              float* __restrict__ mu,
                                              float* __restrict__ ls,
                                              float* __restrict__ z) {
    long t = (long)blockIdx.x * 256 + threadIdx.x;
    int v = (int)(t >> 6), j = (int)(t & 63);
    if (v >= NN) return;
    int beg = row_ptr[v], end = row_ptr[v + 1];
    float acc = 0.f;
    int i = beg;
    for (; i + 4 <= end; i += 4) {
        int s0 = csr_src[i], s1 = csr_src[i + 1], s2 = csr_src[i + 2], s3 = csr_src[i + 3];
        float a0 = dis[s0] * t2[s0 * 64 + j];
        float a1 = dis[s1] * t2[s1 * 64 + j];
        float a2 = dis[s2] * t2[s2 * 64 + j];
        float a3 = dis[s3] * t2[s3 * 64 + j];
        acc += (a0 + a1) + (a2 + a3);
    }
    for (; i < end; ++i) {
        int s = csr_src[i];
        acc += dis[s] * t2[s * 64 + j];
    }
    float dv = dis[v];
    float val = dv * (acc + dv * t2[v * 64 + j]) + ((j < 32) ? bmu[j] : bls[j - 32]);
    float other = __shfl_xor(val, 32);
    if (j < 32) {
        mu[v * 32 + j] = val;
        float lc = fminf(fmaxf(other, -10.0f), 10.0f);
        z[v * 32 + j] = val + eps[v * 32 + j] * expf(lc);
    } else {
        ls[v * 32 + j - 32] = val;
    }
}

// adj_pred[e] = sigmoid(<z[src], z[dst]>), 8 lanes per edge, float4 loads
__global__ __launch_bounds__(256) void k_decode(const float* __restrict__ z,
                                                const int* __restrict__ src,
                                                const int* __restrict__ dst,
                                                float* __restrict__ out) {
    long t = (long)blockIdx.x * 256 + threadIdx.x;
    long e = t >> 3; int l = (int)(t & 7);
    if (e >= NE) return;
    int s = src[e], d = dst[e];
    const float4* z4 = (const float4*)z;
    float4 a = z4[s * 8 + l];
    float4 b = z4[d * 8 + l];
    float p = a.x * b.x + a.y * b.y + a.z * b.z + a.w * b.w;
    p += __shfl_xor(p, 1);
    p += __shfl_xor(p, 2);
    p += __shfl_xor(p, 4);
    if (l == 0) out[e] = 1.0f / (1.0f + expf(-p));
}

extern "C" void kernel_launch(void* const* d_in, const int* in_sizes, int n_in,
                              void* d_out, int out_size, void* d_ws, size_t ws_size,
                              hipStream_t stream) {
    const float* x   = (const float*)d_in[0];
    const int*   ei  = (const int*)d_in[1];
    const float* eps = (const float*)d_in[2];
    const float* W1  = (const float*)d_in[3];
    const float* b1  = (const float*)d_in[4];
    const float* Wmu = (const float*)d_in[5];
    const float* bmu = (const float*)d_in[6];
    const float* Wls = (const float*)d_in[7];
    const float* bls = (const float*)d_in[8];
    const int* src = ei;        // edge_index[0]
    const int* dst = ei + NE;   // edge_index[1]

    float* out = (float*)d_out;
    float* adj = out;                       // [E]
    float* mu  = out + NE;                  // [N,32]
    float* ls  = mu + (long)NN * 32;        // [N,32]

    // workspace layout (all block sizes multiples of 4 elements -> 16B aligned)
    float* dis     = (float*)d_ws;              // NN
    int*   row_ptr = (int*)(dis + NN);          // 100004
    int*   hist    = row_ptr + 100004;          // NN
    int*   partial = hist + NN;                 // 512
    int*   counts  = partial + 512;             // NT*NB_BKT = 76636 -> pad 76640
    int*   ebuf    = counts + 76640;            // NE
    int*   csr_src = ebuf + NE;                 // NE
    float* t       = (float*)(csr_src + NE);    // NN*64  (t1 then t2)
    float* h       = t + (long)NN * 64;         // NN*64
    float* z       = h + (long)NN * 64;         // NN*32

    const int B = 256;
    const int NB_N = (NN + B - 1) / B;          // 391
    const int NB_E = (NE + B - 1) / B;          // 6250

    hipMemsetAsync(hist, 0, (size_t)NN * sizeof(int), stream);

    // CSR build + dis (no contended global atomics)
    k_hist <<<NB_E, B, 0, stream>>>(dst, hist);
    k_dis  <<<NB_N, B, 0, stream>>>(hist, dis);
    k_scan1<<<NB_N, B, 0, stream>>>(hist, row_ptr, partial);
    k_scan2<<<1, 512, 0, stream>>>(partial, NB_N);
    k_scan3<<<NB_N, B, 0, stream>>>(row_ptr, partial);
    k_cnt  <<<NT, B, 0, stream>>>(dst, counts);
    k_offs <<<(NB_BKT + B - 1) / B, B, 0, stream>>>(row_ptr, counts);
    k_place<<<NT, B, 0, stream>>>(src, dst, counts, ebuf);
    k_fill_b<<<NB_BKT, B, 0, stream>>>(row_ptr, ebuf, csr_src);

    // layer 1
    k_gemm1<<<NN / 16, B, 0, stream>>>(x, W1, t);
    k_agg1 <<<(int)(((long)NN * 64 + B - 1) / B), B, 0, stream>>>(t, row_ptr, csr_src, dis, b1, h);

    // layer 2
    k_gemm2<<<NN / 16, B, 0, stream>>>(h, Wmu, Wls, t);
    k_agg2 <<<(int)(((long)NN * 64 + B - 1) / B), B, 0, stream>>>(t, row_ptr, csr_src, dis,
                                                                  bmu, bls, eps, mu, ls, z);

    // decode
    k_decode<<<(int)(((long)NE * 8 + B - 1) / B), B, 0, stream>>>(z, src, dst, adj);
}

// Round 5
// 550.298 us; speedup vs baseline: 1.6530x; 1.0661x over previous
//
#include <hip/hip_runtime.h>
#include <hip/hip_bf16.h>

#define NN 100000
#define NE 1600000
#define W_BKT 128
#define NB_BKT ((NN + W_BKT - 1) / W_BKT)   // 782
#define TILE_E 16384                         // edges per counting-sort tile
#define NT ((NE + TILE_E - 1) / TILE_E)      // 98
// IN=128, HID=64, OUT=32

// ---------------- degree / CSR build ----------------

__global__ __launch_bounds__(256) void k_hist(const int* __restrict__ dst, int* __restrict__ hist) {
    int e = blockIdx.x * 256 + threadIdx.x;
    if (e < NE) atomicAdd(&hist[dst[e]], 1);
}

__global__ __launch_bounds__(256) void k_dis(const int* __restrict__ hist, float* __restrict__ dis) {
    int i = blockIdx.x * 256 + threadIdx.x;
    if (i < NN) dis[i] = rsqrtf((float)(1 + hist[i]));   // +1 self-loop
}

// per-block exclusive scan of hist -> row_ptr(local), block total -> partial[b]
__global__ __launch_bounds__(256) void k_scan1(const int* __restrict__ hist,
                                               int* __restrict__ row_ptr,
                                               int* __restrict__ partial) {
    __shared__ int buf[256];
    int tid = threadIdx.x;
    int i = blockIdx.x * 256 + tid;
    int v = (i < NN) ? hist[i] : 0;
    buf[tid] = v;
    __syncthreads();
    for (int off = 1; off < 256; off <<= 1) {
        int t = (tid >= off) ? buf[tid - off] : 0;
        __syncthreads();
        buf[tid] += t;
        __syncthreads();
    }
    if (i < NN) row_ptr[i] = buf[tid] - v;     // exclusive within block
    if (tid == 255) partial[blockIdx.x] = buf[255];
}

// exclusive scan of 391 block partials (one block of 512)
__global__ __launch_bounds__(512) void k_scan2(int* __restrict__ partial, int nb) {
    __shared__ int buf[512];
    int tid = threadIdx.x;
    int v = (tid < nb) ? partial[tid] : 0;
    buf[tid] = v;
    __syncthreads();
    for (int off = 1; off < 512; off <<= 1) {
        int t = (tid >= off) ? buf[tid - off] : 0;
        __syncthreads();
        buf[tid] += t;
        __syncthreads();
    }
    partial[tid] = buf[tid] - v;   // exclusive
}

// add block offsets; write row_ptr[NN]
__global__ __launch_bounds__(256) void k_scan3(int* __restrict__ row_ptr,
                                               const int* __restrict__ partial) {
    int i = blockIdx.x * 256 + threadIdx.x;
    if (i < NN) row_ptr[i] += partial[blockIdx.x];
    if (i == 0) row_ptr[NN] = NE;
}

// ---- deterministic two-pass bucket sort (NO global atomics) ----

// per-tile bucket histogram via LDS atomics
__global__ __launch_bounds__(256) void k_cnt(const int* __restrict__ dst,
                                             int* __restrict__ counts) {
    __shared__ int hc[NB_BKT];
    int tid = threadIdx.x;
    for (int i = tid; i < NB_BKT; i += 256) hc[i] = 0;
    __syncthreads();
    int base = blockIdx.x * TILE_E;
    int lim = base + TILE_E; if (lim > NE) lim = NE;
    for (int e = base + tid; e < lim; e += 256)
        atomicAdd(&hc[dst[e] >> 7], 1);
    __syncthreads();
    for (int i = tid; i < NB_BKT; i += 256)
        counts[blockIdx.x * NB_BKT + i] = hc[i];
}

// thread per bucket: running sum over tiles, seeded from row_ptr -> base offsets
__global__ __launch_bounds__(256) void k_offs(const int* __restrict__ row_ptr,
                                              int* __restrict__ counts) {
    int b = blockIdx.x * 256 + threadIdx.x;
    if (b >= NB_BKT) return;
    int off = row_ptr[b * W_BKT];
    for (int t = 0; t < NT; ++t) {
        int c = counts[t * NB_BKT + b];
        counts[t * NB_BKT + b] = off;
        off += c;
    }
}

// re-read tile, place packed (src<<7 | d&127) at deterministic positions
__global__ __launch_bounds__(256) void k_place(const int* __restrict__ src,
                                               const int* __restrict__ dst,
                                               const int* __restrict__ counts,
                                               int* __restrict__ ebuf) {
    __shared__ int cur[NB_BKT];
    int tid = threadIdx.x;
    for (int i = tid; i < NB_BKT; i += 256)
        cur[i] = counts[blockIdx.x * NB_BKT + i];
    __syncthreads();
    int base = blockIdx.x * TILE_E;
    int lim = base + TILE_E; if (lim > NE) lim = NE;
    for (int e = base + tid; e < lim; e += 256) {
        int s = src[e], d = dst[e];
        int pos = atomicAdd(&cur[d >> 7], 1);     // LDS atomic, ~21/counter
        ebuf[pos] = (s << 7) | (d & 127);
    }
}

// pass B: one block per bucket; per-node cursors in LDS; contiguous-region writes.
__global__ __launch_bounds__(256) void k_fill_b(const int* __restrict__ row_ptr,
                                                const int* __restrict__ ebuf,
                                                int* __restrict__ csr_src) {
    __shared__ int cur[W_BKT];
    int b = blockIdx.x;
    int v0 = b * W_BKT;
    int tid = threadIdx.x;
    if (tid < W_BKT) {
        int v = v0 + tid;
        cur[tid] = (v < NN) ? row_ptr[v] : NE;
    }
    int vend = v0 + W_BKT; if (vend > NN) vend = NN;
    int beg = row_ptr[v0];
    int end = row_ptr[vend];
    __syncthreads();
    for (int i = beg + tid; i < end; i += 256) {
        int val = ebuf[i];
        int pos = atomicAdd(&cur[val & 127], 1);
        csr_src[pos] = val >> 7;
    }
}

// ---------------- dense transforms ----------------

// t1[N,64] = x[N,128] @ W1[128,64], stored bf16.  16 rows/block, W1+x in LDS.
__global__ __launch_bounds__(256) void k_gemm1(const float* __restrict__ x,
                                               const float* __restrict__ W1,
                                               __hip_bfloat16* __restrict__ t1) {
    __shared__ float Wl[128 * 64];
    __shared__ float Xl[16 * 128];
    int tid = threadIdx.x;
    const float4* W4 = (const float4*)W1;
    float4* Wl4 = (float4*)Wl;
    for (int i = tid; i < 128 * 16; i += 256) Wl4[i] = W4[i];
    long rowbase = (long)blockIdx.x * 16;      // N = 6250 * 16 exactly
    const float4* X4 = (const float4*)(x + rowbase * 128);
    float4* Xl4 = (float4*)Xl;
    for (int i = tid; i < 16 * 32; i += 256) Xl4[i] = X4[i];
    __syncthreads();
    int col = tid & 63, rg = tid >> 6;
    float acc[4] = {0.f, 0.f, 0.f, 0.f};
    for (int k = 0; k < 128; ++k) {
        float w = Wl[k * 64 + col];
#pragma unroll
        for (int i = 0; i < 4; ++i) acc[i] += Xl[(rg * 4 + i) * 128 + k] * w;
    }
#pragma unroll
    for (int i = 0; i < 4; ++i)
        t1[(rowbase + rg * 4 + i) * 64 + col] = __float2bfloat16(acc[i]);
}

// t2[N,64] = h[N,64] @ [Wmu | Wls]  (each [64,32]), stored bf16
__global__ __launch_bounds__(256) void k_gemm2(const float* __restrict__ h,
                                               const float* __restrict__ Wmu,
                                               const float* __restrict__ Wls,
                                               __hip_bfloat16* __restrict__ t2) {
    __shared__ float Wl[64 * 64];
    __shared__ float Hl[16 * 64];
    int tid = threadIdx.x;
    for (int i = tid; i < 64 * 64; i += 256) {
        int k = i >> 6, j = i & 63;
        Wl[i] = (j < 32) ? Wmu[k * 32 + j] : Wls[k * 32 + j - 32];
    }
    long rowbase = (long)blockIdx.x * 16;
    const float4* H4 = (const float4*)(h + rowbase * 64);
    float4* Hl4 = (float4*)Hl;
    for (int i = tid; i < 16 * 16; i += 256) Hl4[i] = H4[i];
    __syncthreads();
    int col = tid & 63, rg = tid >> 6;
    float acc[4] = {0.f, 0.f, 0.f, 0.f};
    for (int k = 0; k < 64; ++k) {
        float w = Wl[k * 64 + col];
#pragma unroll
        for (int i = 0; i < 4; ++i) acc[i] += Hl[(rg * 4 + i) * 64 + k] * w;
    }
#pragma unroll
    for (int i = 0; i < 4; ++i)
        t2[(rowbase + rg * 4 + i) * 64 + col] = __float2bfloat16(acc[i]);
}

// ---------------- fused gather-aggregations (bf16 feature rows) ----------------

// h[v] = l2normalize(relu(dis[v]*(sum_s dis[s]*t1[s] + dis[v]*t1[v]) + b1))
__global__ __launch_bounds__(256) void k_agg1(const __hip_bfloat16* __restrict__ t1,
                                              const int* __restrict__ row_ptr,
                                              const int* __restrict__ csr_src,
                                              const float* __restrict__ dis,
                                              const float* __restrict__ b1,
                                              float* __restrict__ h) {
    long t = (long)blockIdx.x * 256 + threadIdx.x;
    int v = (int)(t >> 6), j = (int)(t & 63);
    if (v >= NN) return;
    int beg = row_ptr[v], end = row_ptr[v + 1];
    float acc = 0.f;
    int i = beg;
    for (; i + 4 <= end; i += 4) {
        int s0 = csr_src[i], s1 = csr_src[i + 1], s2 = csr_src[i + 2], s3 = csr_src[i + 3];
        float a0 = dis[s0] * __bfloat162float(t1[s0 * 64 + j]);
        float a1 = dis[s1] * __bfloat162float(t1[s1 * 64 + j]);
        float a2 = dis[s2] * __bfloat162float(t1[s2 * 64 + j]);
        float a3 = dis[s3] * __bfloat162float(t1[s3 * 64 + j]);
        acc += (a0 + a1) + (a2 + a3);
    }
    for (; i < end; ++i) {
        int s = csr_src[i];
        acc += dis[s] * __bfloat162float(t1[s * 64 + j]);
    }
    float dv = dis[v];
    float val = dv * (acc + dv * __bfloat162float(t1[v * 64 + j])) + b1[j];
    val = fmaxf(val, 0.0f);
    float ss = val * val;
#pragma unroll
    for (int m = 1; m < 64; m <<= 1) ss += __shfl_xor(ss, m);
    float scale = 1.0f / fmaxf(sqrtf(ss), 1e-12f);
    h[v * 64 + j] = val * scale;
}

// layer-2 aggregation fused with bias + reparametrize; writes mu, ls, z
__global__ __launch_bounds__(256) void k_agg2(const __hip_bfloat16* __restrict__ t2,
                                              const int* __restrict__ row_ptr,
                                              const int* __restrict__ csr_src,
                                              const float* __restrict__ dis,
                                              const float* __restrict__ bmu,
                                              const float* __restrict__ bls,
                                              const float* __restrict__ eps,
                                              float* __restrict__ mu,
                                              float* __restrict__ ls,
                                              float* __restrict__ z) {
    long t = (long)blockIdx.x * 256 + threadIdx.x;
    int v = (int)(t >> 6), j = (int)(t & 63);
    if (v >= NN) return;
    int beg = row_ptr[v], end = row_ptr[v + 1];
    float acc = 0.f;
    int i = beg;
    for (; i + 4 <= end; i += 4) {
        int s0 = csr_src[i], s1 = csr_src[i + 1], s2 = csr_src[i + 2], s3 = csr_src[i + 3];
        float a0 = dis[s0] * __bfloat162float(t2[s0 * 64 + j]);
        float a1 = dis[s1] * __bfloat162float(t2[s1 * 64 + j]);
        float a2 = dis[s2] * __bfloat162float(t2[s2 * 64 + j]);
        float a3 = dis[s3] * __bfloat162float(t2[s3 * 64 + j]);
        acc += (a0 + a1) + (a2 + a3);
    }
    for (; i < end; ++i) {
        int s = csr_src[i];
        acc += dis[s] * __bfloat162float(t2[s * 64 + j]);
    }
    float dv = dis[v];
    float val = dv * (acc + dv * __bfloat162float(t2[v * 64 + j])) + ((j < 32) ? bmu[j] : bls[j - 32]);
    float other = __shfl_xor(val, 32);
    if (j < 32) {
        mu[v * 32 + j] = val;
        float lc = fminf(fmaxf(other, -10.0f), 10.0f);
        z[v * 32 + j] = val + eps[v * 32 + j] * expf(lc);
    } else {
        ls[v * 32 + j - 32] = val;
    }
}

// adj_pred[e] = sigmoid(<z[src], z[dst]>), 8 lanes per edge, float4 loads
__global__ __launch_bounds__(256) void k_decode(const float* __restrict__ z,
                                                const int* __restrict__ src,
                                                const int* __restrict__ dst,
                                                float* __restrict__ out) {
    long t = (long)blockIdx.x * 256 + threadIdx.x;
    long e = t >> 3; int l = (int)(t & 7);
    if (e >= NE) return;
    int s = src[e], d = dst[e];
    const float4* z4 = (const float4*)z;
    float4 a = z4[s * 8 + l];
    float4 b = z4[d * 8 + l];
    float p = a.x * b.x + a.y * b.y + a.z * b.z + a.w * b.w;
    p += __shfl_xor(p, 1);
    p += __shfl_xor(p, 2);
    p += __shfl_xor(p, 4);
    if (l == 0) out[e] = 1.0f / (1.0f + expf(-p));
}

extern "C" void kernel_launch(void* const* d_in, const int* in_sizes, int n_in,
                              void* d_out, int out_size, void* d_ws, size_t ws_size,
                              hipStream_t stream) {
    const float* x   = (const float*)d_in[0];
    const int*   ei  = (const int*)d_in[1];
    const float* eps = (const float*)d_in[2];
    const float* W1  = (const float*)d_in[3];
    const float* b1  = (const float*)d_in[4];
    const float* Wmu = (const float*)d_in[5];
    const float* bmu = (const float*)d_in[6];
    const float* Wls = (const float*)d_in[7];
    const float* bls = (const float*)d_in[8];
    const int* src = ei;        // edge_index[0]
    const int* dst = ei + NE;   // edge_index[1]

    float* out = (float*)d_out;
    float* adj = out;                       // [E]
    float* mu  = out + NE;                  // [N,32]
    float* ls  = mu + (long)NN * 32;        // [N,32]

    // workspace layout (all block byte sizes multiples of 16)
    float* dis     = (float*)d_ws;              // NN
    int*   row_ptr = (int*)(dis + NN);          // 100004
    int*   hist    = row_ptr + 100004;          // NN
    int*   partial = hist + NN;                 // 512
    int*   counts  = partial + 512;             // NT*NB_BKT = 76636 -> pad 76640
    int*   ebuf    = counts + 76640;            // NE
    int*   csr_src = ebuf + NE;                 // NE
    __hip_bfloat16* t = (__hip_bfloat16*)(csr_src + NE);  // NN*64 bf16 (t1 then t2)
    float* h       = (float*)(t + (long)NN * 64);         // NN*64 f32
    float* z       = h + (long)NN * 64;                   // NN*32 f32

    const int B = 256;
    const int NB_N = (NN + B - 1) / B;          // 391
    const int NB_E = (NE + B - 1) / B;          // 6250

    hipMemsetAsync(hist, 0, (size_t)NN * sizeof(int), stream);

    // CSR build + dis (no contended global atomics)
    k_hist <<<NB_E, B, 0, stream>>>(dst, hist);
    k_dis  <<<NB_N, B, 0, stream>>>(hist, dis);
    k_scan1<<<NB_N, B, 0, stream>>>(hist, row_ptr, partial);
    k_scan2<<<1, 512, 0, stream>>>(partial, NB_N);
    k_scan3<<<NB_N, B, 0, stream>>>(row_ptr, partial);
    k_cnt  <<<NT, B, 0, stream>>>(dst, counts);
    k_offs <<<(NB_BKT + B - 1) / B, B, 0, stream>>>(row_ptr, counts);
    k_place<<<NT, B, 0, stream>>>(src, dst, counts, ebuf);
    k_fill_b<<<NB_BKT, B, 0, stream>>>(row_ptr, ebuf, csr_src);

    // layer 1
    k_gemm1<<<NN / 16, B, 0, stream>>>(x, W1, t);
    k_agg1 <<<(int)(((long)NN * 64 + B - 1) / B), B, 0, stream>>>(t, row_ptr, csr_src, dis, b1, h);

    // layer 2
    k_gemm2<<<NN / 16, B, 0, stream>>>(h, Wmu, Wls, t);
    k_agg2 <<<(int)(((long)NN * 64 + B - 1) / B), B, 0, stream>>>(t, row_ptr, csr_src, dis,
                                                                  bmu, bls, eps, mu, ls, z);

    // decode
    k_decode<<<(int)(((long)NE * 8 + B - 1) / B), B, 0, stream>>>(z, src, dst, adj);
}

// Round 6
// 511.144 us; speedup vs baseline: 1.7797x; 1.0766x over previous
//
#include <hip/hip_runtime.h>
#include <hip/hip_bf16.h>

#define NN 100000
#define NE 1600000
#define W_BKT 128
#define NB_BKT ((NN + W_BKT - 1) / W_BKT)   // 782
#define TILE_E 16384                         // edges per counting-sort tile
#define NT ((NE + TILE_E - 1) / TILE_E)      // 98
// IN=128, HID=64, OUT=32

// ---------------- degree / CSR build ----------------

__global__ __launch_bounds__(256) void k_hist(const int* __restrict__ dst, int* __restrict__ hist) {
    int e = blockIdx.x * 256 + threadIdx.x;
    if (e < NE) atomicAdd(&hist[dst[e]], 1);
}

__global__ __launch_bounds__(256) void k_dis(const int* __restrict__ hist, float* __restrict__ dis) {
    int i = blockIdx.x * 256 + threadIdx.x;
    if (i < NN) dis[i] = rsqrtf((float)(1 + hist[i]));   // +1 self-loop
}

// per-block exclusive scan of hist -> row_ptr(local), block total -> partial[b]
__global__ __launch_bounds__(256) void k_scan1(const int* __restrict__ hist,
                                               int* __restrict__ row_ptr,
                                               int* __restrict__ partial) {
    __shared__ int buf[256];
    int tid = threadIdx.x;
    int i = blockIdx.x * 256 + tid;
    int v = (i < NN) ? hist[i] : 0;
    buf[tid] = v;
    __syncthreads();
    for (int off = 1; off < 256; off <<= 1) {
        int t = (tid >= off) ? buf[tid - off] : 0;
        __syncthreads();
        buf[tid] += t;
        __syncthreads();
    }
    if (i < NN) row_ptr[i] = buf[tid] - v;     // exclusive within block
    if (tid == 255) partial[blockIdx.x] = buf[255];
}

// exclusive scan of 391 block partials (one block of 512)
__global__ __launch_bounds__(512) void k_scan2(int* __restrict__ partial, int nb) {
    __shared__ int buf[512];
    int tid = threadIdx.x;
    int v = (tid < nb) ? partial[tid] : 0;
    buf[tid] = v;
    __syncthreads();
    for (int off = 1; off < 512; off <<= 1) {
        int t = (tid >= off) ? buf[tid - off] : 0;
        __syncthreads();
        buf[tid] += t;
        __syncthreads();
    }
    partial[tid] = buf[tid] - v;   // exclusive
}

// add block offsets; write row_ptr[NN]
__global__ __launch_bounds__(256) void k_scan3(int* __restrict__ row_ptr,
                                               const int* __restrict__ partial) {
    int i = blockIdx.x * 256 + threadIdx.x;
    if (i < NN) row_ptr[i] += partial[blockIdx.x];
    if (i == 0) row_ptr[NN] = NE;
}

// ---- deterministic two-pass bucket sort (NO global atomics) ----

__global__ __launch_bounds__(256) void k_cnt(const int* __restrict__ dst,
                                             int* __restrict__ counts) {
    __shared__ int hc[NB_BKT];
    int tid = threadIdx.x;
    for (int i = tid; i < NB_BKT; i += 256) hc[i] = 0;
    __syncthreads();
    int base = blockIdx.x * TILE_E;
    int lim = base + TILE_E; if (lim > NE) lim = NE;
    for (int e = base + tid; e < lim; e += 256)
        atomicAdd(&hc[dst[e] >> 7], 1);
    __syncthreads();
    for (int i = tid; i < NB_BKT; i += 256)
        counts[blockIdx.x * NB_BKT + i] = hc[i];
}

__global__ __launch_bounds__(256) void k_offs(const int* __restrict__ row_ptr,
                                              int* __restrict__ counts) {
    int b = blockIdx.x * 256 + threadIdx.x;
    if (b >= NB_BKT) return;
    int off = row_ptr[b * W_BKT];
    for (int t = 0; t < NT; ++t) {
        int c = counts[t * NB_BKT + b];
        counts[t * NB_BKT + b] = off;
        off += c;
    }
}

__global__ __launch_bounds__(256) void k_place(const int* __restrict__ src,
                                               const int* __restrict__ dst,
                                               const int* __restrict__ counts,
                                               int* __restrict__ ebuf) {
    __shared__ int cur[NB_BKT];
    int tid = threadIdx.x;
    for (int i = tid; i < NB_BKT; i += 256)
        cur[i] = counts[blockIdx.x * NB_BKT + i];
    __syncthreads();
    int base = blockIdx.x * TILE_E;
    int lim = base + TILE_E; if (lim > NE) lim = NE;
    for (int e = base + tid; e < lim; e += 256) {
        int s = src[e], d = dst[e];
        int pos = atomicAdd(&cur[d >> 7], 1);     // LDS atomic, ~21/counter
        ebuf[pos] = (s << 7) | (d & 127);
    }
}

__global__ __launch_bounds__(256) void k_fill_b(const int* __restrict__ row_ptr,
                                                const int* __restrict__ ebuf,
                                                int* __restrict__ csr_src) {
    __shared__ int cur[W_BKT];
    int b = blockIdx.x;
    int v0 = b * W_BKT;
    int tid = threadIdx.x;
    if (tid < W_BKT) {
        int v = v0 + tid;
        cur[tid] = (v < NN) ? row_ptr[v] : NE;
    }
    int vend = v0 + W_BKT; if (vend > NN) vend = NN;
    int beg = row_ptr[v0];
    int end = row_ptr[vend];
    __syncthreads();
    for (int i = beg + tid; i < end; i += 256) {
        int val = ebuf[i];
        int pos = atomicAdd(&cur[val & 127], 1);
        csr_src[pos] = val >> 7;
    }
}

// ---------------- dense transforms ----------------

// t1[N,64] = x[N,128] @ W1[128,64], stored bf16.  16 rows/block, W1+x in LDS.
__global__ __launch_bounds__(256) void k_gemm1(const float* __restrict__ x,
                                               const float* __restrict__ W1,
                                               __hip_bfloat16* __restrict__ t1) {
    __shared__ float Wl[128 * 64];
    __shared__ float Xl[16 * 128];
    int tid = threadIdx.x;
    const float4* W4 = (const float4*)W1;
    float4* Wl4 = (float4*)Wl;
    for (int i = tid; i < 128 * 16; i += 256) Wl4[i] = W4[i];
    long rowbase = (long)blockIdx.x * 16;      // N = 6250 * 16 exactly
    const float4* X4 = (const float4*)(x + rowbase * 128);
    float4* Xl4 = (float4*)Xl;
    for (int i = tid; i < 16 * 32; i += 256) Xl4[i] = X4[i];
    __syncthreads();
    int col = tid & 63, rg = tid >> 6;
    float acc[4] = {0.f, 0.f, 0.f, 0.f};
    for (int k = 0; k < 128; ++k) {
        float w = Wl[k * 64 + col];
#pragma unroll
        for (int i = 0; i < 4; ++i) acc[i] += Xl[(rg * 4 + i) * 128 + k] * w;
    }
#pragma unroll
    for (int i = 0; i < 4; ++i)
        t1[(rowbase + rg * 4 + i) * 64 + col] = __float2bfloat16(acc[i]);
}

// t2[N,64] = h[N,64] @ [Wmu | Wls]  (each [64,32]), stored bf16
__global__ __launch_bounds__(256) void k_gemm2(const float* __restrict__ h,
                                               const float* __restrict__ Wmu,
                                               const float* __restrict__ Wls,
                                               __hip_bfloat16* __restrict__ t2) {
    __shared__ float Wl[64 * 64];
    __shared__ float Hl[16 * 64];
    int tid = threadIdx.x;
    for (int i = tid; i < 64 * 64; i += 256) {
        int k = i >> 6, j = i & 63;
        Wl[i] = (j < 32) ? Wmu[k * 32 + j] : Wls[k * 32 + j - 32];
    }
    long rowbase = (long)blockIdx.x * 16;
    const float4* H4 = (const float4*)(h + rowbase * 64);
    float4* Hl4 = (float4*)Hl;
    for (int i = tid; i < 16 * 16; i += 256) Hl4[i] = H4[i];
    __syncthreads();
    int col = tid & 63, rg = tid >> 6;
    float acc[4] = {0.f, 0.f, 0.f, 0.f};
    for (int k = 0; k < 64; ++k) {
        float w = Wl[k * 64 + col];
#pragma unroll
        for (int i = 0; i < 4; ++i) acc[i] += Hl[(rg * 4 + i) * 64 + k] * w;
    }
#pragma unroll
    for (int i = 0; i < 4; ++i)
        t2[(rowbase + rg * 4 + i) * 64 + col] = __float2bfloat16(acc[i]);
}

// ---------------- fused gather-aggregations ----------------
// Layout: 2 nodes per wave (32 lanes each), each lane covers dims 2*j2, 2*j2+1
// via bf16x2 loads.  Indices + dis weights prefetched lane-parallel (1 coalesced
// load + 1 gather for up to 32 edges), broadcast per-edge via __shfl width 32 —
// removes the csr->gather serial dependency so row gathers pipeline deeply.

// h[v] = l2normalize(relu(dis[v]*(sum_s dis[s]*t1[s] + dis[v]*t1[v]) + b1))
__global__ __launch_bounds__(256) void k_agg1(const __hip_bfloat162* __restrict__ tv,
                                              const int* __restrict__ row_ptr,
                                              const int* __restrict__ csr_src,
                                              const float* __restrict__ dis,
                                              const float* __restrict__ b1,
                                              float* __restrict__ h) {
    int lane = threadIdx.x & 63;
    int j2 = lane & 31;
    int v = blockIdx.x * 8 + (threadIdx.x >> 6) * 2 + (lane >> 5);   // NN = 12500*8
    int beg = row_ptr[v], end = row_ptr[v + 1];
    float acc0 = 0.f, acc1 = 0.f;
    for (int base = beg; base < end; base += 32) {
        int cnt = end - base; if (cnt > 32) cnt = 32;
        int idx = 0; float wgt = 0.f;
        if (j2 < cnt) { idx = csr_src[base + j2]; wgt = dis[idx]; }
        int k = 0;
        for (; k + 4 <= cnt; k += 4) {
            int s0 = __shfl(idx, k, 32), s1 = __shfl(idx, k + 1, 32),
                s2 = __shfl(idx, k + 2, 32), s3 = __shfl(idx, k + 3, 32);
            float w0 = __shfl(wgt, k, 32), w1 = __shfl(wgt, k + 1, 32),
                  w2 = __shfl(wgt, k + 2, 32), w3 = __shfl(wgt, k + 3, 32);
            __hip_bfloat162 r0 = tv[s0 * 32 + j2];
            __hip_bfloat162 r1 = tv[s1 * 32 + j2];
            __hip_bfloat162 r2 = tv[s2 * 32 + j2];
            __hip_bfloat162 r3 = tv[s3 * 32 + j2];
            acc0 += w0 * __bfloat162float(r0.x); acc1 += w0 * __bfloat162float(r0.y);
            acc0 += w1 * __bfloat162float(r1.x); acc1 += w1 * __bfloat162float(r1.y);
            acc0 += w2 * __bfloat162float(r2.x); acc1 += w2 * __bfloat162float(r2.y);
            acc0 += w3 * __bfloat162float(r3.x); acc1 += w3 * __bfloat162float(r3.y);
        }
        for (; k < cnt; ++k) {
            int s = __shfl(idx, k, 32);
            float w = __shfl(wgt, k, 32);
            __hip_bfloat162 r = tv[s * 32 + j2];
            acc0 += w * __bfloat162float(r.x); acc1 += w * __bfloat162float(r.y);
        }
    }
    float dv = dis[v];
    __hip_bfloat162 rv = tv[v * 32 + j2];
    float val0 = dv * (acc0 + dv * __bfloat162float(rv.x)) + b1[2 * j2];
    float val1 = dv * (acc1 + dv * __bfloat162float(rv.y)) + b1[2 * j2 + 1];
    val0 = fmaxf(val0, 0.0f);
    val1 = fmaxf(val1, 0.0f);
    float ss = val0 * val0 + val1 * val1;
#pragma unroll
    for (int m = 1; m < 32; m <<= 1) ss += __shfl_xor(ss, m);
    float scale = 1.0f / fmaxf(sqrtf(ss), 1e-12f);
    float2* h2 = (float2*)h;
    h2[v * 32 + j2] = make_float2(val0 * scale, val1 * scale);
}

// layer-2 aggregation fused with bias + reparametrize; writes mu, ls, z
__global__ __launch_bounds__(256) void k_agg2(const __hip_bfloat162* __restrict__ tv,
                                              const int* __restrict__ row_ptr,
                                              const int* __restrict__ csr_src,
                                              const float* __restrict__ dis,
                                              const float* __restrict__ bmu,
                                              const float* __restrict__ bls,
                                              const float* __restrict__ eps,
                                              float* __restrict__ mu,
                                              float* __restrict__ ls,
                                              float* __restrict__ z) {
    int lane = threadIdx.x & 63;
    int j2 = lane & 31;
    int v = blockIdx.x * 8 + (threadIdx.x >> 6) * 2 + (lane >> 5);
    int beg = row_ptr[v], end = row_ptr[v + 1];
    float acc0 = 0.f, acc1 = 0.f;
    for (int base = beg; base < end; base += 32) {
        int cnt = end - base; if (cnt > 32) cnt = 32;
        int idx = 0; float wgt = 0.f;
        if (j2 < cnt) { idx = csr_src[base + j2]; wgt = dis[idx]; }
        int k = 0;
        for (; k + 4 <= cnt; k += 4) {
            int s0 = __shfl(idx, k, 32), s1 = __shfl(idx, k + 1, 32),
                s2 = __shfl(idx, k + 2, 32), s3 = __shfl(idx, k + 3, 32);
            float w0 = __shfl(wgt, k, 32), w1 = __shfl(wgt, k + 1, 32),
                  w2 = __shfl(wgt, k + 2, 32), w3 = __shfl(wgt, k + 3, 32);
            __hip_bfloat162 r0 = tv[s0 * 32 + j2];
            __hip_bfloat162 r1 = tv[s1 * 32 + j2];
            __hip_bfloat162 r2 = tv[s2 * 32 + j2];
            __hip_bfloat162 r3 = tv[s3 * 32 + j2];
            acc0 += w0 * __bfloat162float(r0.x); acc1 += w0 * __bfloat162float(r0.y);
            acc0 += w1 * __bfloat162float(r1.x); acc1 += w1 * __bfloat162float(r1.y);
            acc0 += w2 * __bfloat162float(r2.x); acc1 += w2 * __bfloat162float(r2.y);
            acc0 += w3 * __bfloat162float(r3.x); acc1 += w3 * __bfloat162float(r3.y);
        }
        for (; k < cnt; ++k) {
            int s = __shfl(idx, k, 32);
            float w = __shfl(wgt, k, 32);
            __hip_bfloat162 r = tv[s * 32 + j2];
            acc0 += w * __bfloat162float(r.x); acc1 += w * __bfloat162float(r.y);
        }
    }
    float dv = dis[v];
    __hip_bfloat162 rv = tv[v * 32 + j2];
    // dims 2*j2, 2*j2+1: j2<16 -> mu dims, j2>=16 -> logstd dims
    float bb0 = (j2 < 16) ? bmu[2 * j2]     : bls[2 * j2 - 32];
    float bb1 = (j2 < 16) ? bmu[2 * j2 + 1] : bls[2 * j2 - 31];
    float val0 = dv * (acc0 + dv * __bfloat162float(rv.x)) + bb0;
    float val1 = dv * (acc1 + dv * __bfloat162float(rv.y)) + bb1;
    // lane j2 (<16) holds mu dims (2j2,2j2+1); lane j2+16 holds ls of same dims
    float o0 = __shfl_xor(val0, 16);
    float o1 = __shfl_xor(val1, 16);
    float2* mu2 = (float2*)mu;
    float2* ls2 = (float2*)ls;
    float2* z2  = (float2*)z;
    const float2* e2 = (const float2*)eps;
    if (j2 < 16) {
        mu2[v * 16 + j2] = make_float2(val0, val1);
        float2 ev = e2[v * 16 + j2];
        float l0 = fminf(fmaxf(o0, -10.0f), 10.0f);
        float l1 = fminf(fmaxf(o1, -10.0f), 10.0f);
        z2[v * 16 + j2] = make_float2(val0 + ev.x * expf(l0),
                                      val1 + ev.y * expf(l1));
    } else {
        ls2[v * 16 + (j2 - 16)] = make_float2(val0, val1);
    }
}

// adj_pred[e] = sigmoid(<z[src], z[dst]>), 8 lanes per edge, float4 loads
__global__ __launch_bounds__(256) void k_decode(const float* __restrict__ z,
                                                const int* __restrict__ src,
                                                const int* __restrict__ dst,
                                                float* __restrict__ out) {
    long t = (long)blockIdx.x * 256 + threadIdx.x;
    long e = t >> 3; int l = (int)(t & 7);
    if (e >= NE) return;
    int s = src[e], d = dst[e];
    const float4* z4 = (const float4*)z;
    float4 a = z4[s * 8 + l];
    float4 b = z4[d * 8 + l];
    float p = a.x * b.x + a.y * b.y + a.z * b.z + a.w * b.w;
    p += __shfl_xor(p, 1);
    p += __shfl_xor(p, 2);
    p += __shfl_xor(p, 4);
    if (l == 0) out[e] = 1.0f / (1.0f + expf(-p));
}

extern "C" void kernel_launch(void* const* d_in, const int* in_sizes, int n_in,
                              void* d_out, int out_size, void* d_ws, size_t ws_size,
                              hipStream_t stream) {
    const float* x   = (const float*)d_in[0];
    const int*   ei  = (const int*)d_in[1];
    const float* eps = (const float*)d_in[2];
    const float* W1  = (const float*)d_in[3];
    const float* b1  = (const float*)d_in[4];
    const float* Wmu = (const float*)d_in[5];
    const float* bmu = (const float*)d_in[6];
    const float* Wls = (const float*)d_in[7];
    const float* bls = (const float*)d_in[8];
    const int* src = ei;        // edge_index[0]
    const int* dst = ei + NE;   // edge_index[1]

    float* out = (float*)d_out;
    float* adj = out;                       // [E]
    float* mu  = out + NE;                  // [N,32]
    float* ls  = mu + (long)NN * 32;        // [N,32]

    // workspace layout (all block byte sizes multiples of 16)
    float* dis     = (float*)d_ws;              // NN
    int*   row_ptr = (int*)(dis + NN);          // 100004
    int*   hist    = row_ptr + 100004;          // NN
    int*   partial = hist + NN;                 // 512
    int*   counts  = partial + 512;             // NT*NB_BKT = 76636 -> pad 76640
    int*   ebuf    = counts + 76640;            // NE
    int*   csr_src = ebuf + NE;                 // NE
    __hip_bfloat16* t = (__hip_bfloat16*)(csr_src + NE);  // NN*64 bf16 (t1 then t2)
    float* h       = (float*)(t + (long)NN * 64);         // NN*64 f32
    float* z       = h + (long)NN * 64;                   // NN*32 f32

    const int B = 256;
    const int NB_N = (NN + B - 1) / B;          // 391
    const int NB_E = (NE + B - 1) / B;          // 6250

    hipMemsetAsync(hist, 0, (size_t)NN * sizeof(int), stream);

    // CSR build + dis (no contended global atomics)
    k_hist <<<NB_E, B, 0, stream>>>(dst, hist);
    k_dis  <<<NB_N, B, 0, stream>>>(hist, dis);
    k_scan1<<<NB_N, B, 0, stream>>>(hist, row_ptr, partial);
    k_scan2<<<1, 512, 0, stream>>>(partial, NB_N);
    k_scan3<<<NB_N, B, 0, stream>>>(row_ptr, partial);
    k_cnt  <<<NT, B, 0, stream>>>(dst, counts);
    k_offs <<<(NB_BKT + B - 1) / B, B, 0, stream>>>(row_ptr, counts);
    k_place<<<NT, B, 0, stream>>>(src, dst, counts, ebuf);
    k_fill_b<<<NB_BKT, B, 0, stream>>>(row_ptr, ebuf, csr_src);

    // layer 1
    k_gemm1<<<NN / 16, B, 0, stream>>>(x, W1, t);
    k_agg1 <<<NN / 8, B, 0, stream>>>((const __hip_bfloat162*)t, row_ptr, csr_src, dis, b1, h);

    // layer 2
    k_gemm2<<<NN / 16, B, 0, stream>>>(h, Wmu, Wls, t);
    k_agg2 <<<NN / 8, B, 0, stream>>>((const __hip_bfloat162*)t, row_ptr, csr_src, dis,
                                      bmu, bls, eps, mu, ls, z);

    // decode
    k_decode<<<(int)(((long)NE * 8 + B - 1) / B), B, 0, stream>>>(z, src, dst, adj);
}

// Round 7
// 454.670 us; speedup vs baseline: 2.0007x; 1.1242x over previous
//
#include <hip/hip_runtime.h>
#include <hip/hip_fp16.h>

#define NN 100000
#define NE 1600000
#define W_BKT 128
#define NB_BKT ((NN + W_BKT - 1) / W_BKT)   // 782
#define TILE_E 16384                         // edges per counting-sort tile
#define NT ((NE + TILE_E - 1) / TILE_E)      // 98
// IN=128, HID=64, OUT=32

typedef _Float16 half2v __attribute__((ext_vector_type(2)));
typedef _Float16 half8v __attribute__((ext_vector_type(8)));

// ---------------- degree / CSR build ----------------

__global__ __launch_bounds__(256) void k_hist(const int* __restrict__ dst, int* __restrict__ hist) {
    int e = blockIdx.x * 256 + threadIdx.x;
    if (e < NE) atomicAdd(&hist[dst[e]], 1);
}

__global__ __launch_bounds__(256) void k_dis(const int* __restrict__ hist, float* __restrict__ dis) {
    int i = blockIdx.x * 256 + threadIdx.x;
    if (i < NN) dis[i] = rsqrtf((float)(1 + hist[i]));   // +1 self-loop
}

// per-block exclusive scan of hist -> row_ptr(local), block total -> partial[b]
__global__ __launch_bounds__(256) void k_scan1(const int* __restrict__ hist,
                                               int* __restrict__ row_ptr,
                                               int* __restrict__ partial) {
    __shared__ int buf[256];
    int tid = threadIdx.x;
    int i = blockIdx.x * 256 + tid;
    int v = (i < NN) ? hist[i] : 0;
    buf[tid] = v;
    __syncthreads();
    for (int off = 1; off < 256; off <<= 1) {
        int t = (tid >= off) ? buf[tid - off] : 0;
        __syncthreads();
        buf[tid] += t;
        __syncthreads();
    }
    if (i < NN) row_ptr[i] = buf[tid] - v;     // exclusive within block
    if (tid == 255) partial[blockIdx.x] = buf[255];
}

// exclusive scan of 391 block partials (one block of 512)
__global__ __launch_bounds__(512) void k_scan2(int* __restrict__ partial, int nb) {
    __shared__ int buf[512];
    int tid = threadIdx.x;
    int v = (tid < nb) ? partial[tid] : 0;
    buf[tid] = v;
    __syncthreads();
    for (int off = 1; off < 512; off <<= 1) {
        int t = (tid >= off) ? buf[tid - off] : 0;
        __syncthreads();
        buf[tid] += t;
        __syncthreads();
    }
    partial[tid] = buf[tid] - v;   // exclusive
}

// add block offsets; write row_ptr[NN]
__global__ __launch_bounds__(256) void k_scan3(int* __restrict__ row_ptr,
                                               const int* __restrict__ partial) {
    int i = blockIdx.x * 256 + threadIdx.x;
    if (i < NN) row_ptr[i] += partial[blockIdx.x];
    if (i == 0) row_ptr[NN] = NE;
}

// ---- deterministic two-pass bucket sort (NO global atomics) ----

__global__ __launch_bounds__(256) void k_cnt(const int* __restrict__ dst,
                                             int* __restrict__ counts) {
    __shared__ int hc[NB_BKT];
    int tid = threadIdx.x;
    for (int i = tid; i < NB_BKT; i += 256) hc[i] = 0;
    __syncthreads();
    int base = blockIdx.x * TILE_E;
    int lim = base + TILE_E; if (lim > NE) lim = NE;
    for (int e = base + tid; e < lim; e += 256)
        atomicAdd(&hc[dst[e] >> 7], 1);
    __syncthreads();
    for (int i = tid; i < NB_BKT; i += 256)
        counts[blockIdx.x * NB_BKT + i] = hc[i];
}

__global__ __launch_bounds__(256) void k_offs(const int* __restrict__ row_ptr,
                                              int* __restrict__ counts) {
    int b = blockIdx.x * 256 + threadIdx.x;
    if (b >= NB_BKT) return;
    int off = row_ptr[b * W_BKT];
    for (int t = 0; t < NT; ++t) {
        int c = counts[t * NB_BKT + b];
        counts[t * NB_BKT + b] = off;
        off += c;
    }
}

__global__ __launch_bounds__(256) void k_place(const int* __restrict__ src,
                                               const int* __restrict__ dst,
                                               const int* __restrict__ counts,
                                               int* __restrict__ ebuf) {
    __shared__ int cur[NB_BKT];
    int tid = threadIdx.x;
    for (int i = tid; i < NB_BKT; i += 256)
        cur[i] = counts[blockIdx.x * NB_BKT + i];
    __syncthreads();
    int base = blockIdx.x * TILE_E;
    int lim = base + TILE_E; if (lim > NE) lim = NE;
    for (int e = base + tid; e < lim; e += 256) {
        int s = src[e], d = dst[e];
        int pos = atomicAdd(&cur[d >> 7], 1);     // LDS atomic, ~21/counter
        ebuf[pos] = (s << 7) | (d & 127);
    }
}

__global__ __launch_bounds__(256) void k_fill_b(const int* __restrict__ row_ptr,
                                                const int* __restrict__ ebuf,
                                                int* __restrict__ csr_src) {
    __shared__ int cur[W_BKT];
    int b = blockIdx.x;
    int v0 = b * W_BKT;
    int tid = threadIdx.x;
    if (tid < W_BKT) {
        int v = v0 + tid;
        cur[tid] = (v < NN) ? row_ptr[v] : NE;
    }
    int vend = v0 + W_BKT; if (vend > NN) vend = NN;
    int beg = row_ptr[v0];
    int end = row_ptr[vend];
    __syncthreads();
    for (int i = beg + tid; i < end; i += 256) {
        int val = ebuf[i];
        int pos = atomicAdd(&cur[val & 127], 1);
        csr_src[pos] = val >> 7;
    }
}

// ---------------- dense transforms ----------------

// t1[N,64] = x[N,128] @ W1[128,64], stored fp16.  16 rows/block, W1+x in LDS.
__global__ __launch_bounds__(256) void k_gemm1(const float* __restrict__ x,
                                               const float* __restrict__ W1,
                                               _Float16* __restrict__ t1) {
    __shared__ float Wl[128 * 64];
    __shared__ float Xl[16 * 128];
    int tid = threadIdx.x;
    const float4* W4 = (const float4*)W1;
    float4* Wl4 = (float4*)Wl;
    for (int i = tid; i < 128 * 16; i += 256) Wl4[i] = W4[i];
    long rowbase = (long)blockIdx.x * 16;      // N = 6250 * 16 exactly
    const float4* X4 = (const float4*)(x + rowbase * 128);
    float4* Xl4 = (float4*)Xl;
    for (int i = tid; i < 16 * 32; i += 256) Xl4[i] = X4[i];
    __syncthreads();
    int col = tid & 63, rg = tid >> 6;
    float acc[4] = {0.f, 0.f, 0.f, 0.f};
    for (int k = 0; k < 128; ++k) {
        float w = Wl[k * 64 + col];
#pragma unroll
        for (int i = 0; i < 4; ++i) acc[i] += Xl[(rg * 4 + i) * 128 + k] * w;
    }
#pragma unroll
    for (int i = 0; i < 4; ++i)
        t1[(rowbase + rg * 4 + i) * 64 + col] = (_Float16)acc[i];
}

// t2[N,64] = h[N,64] @ [Wmu | Wls]  (each [64,32]), stored fp16
__global__ __launch_bounds__(256) void k_gemm2(const float* __restrict__ h,
                                               const float* __restrict__ Wmu,
                                               const float* __restrict__ Wls,
                                               _Float16* __restrict__ t2) {
    __shared__ float Wl[64 * 64];
    __shared__ float Hl[16 * 64];
    int tid = threadIdx.x;
    for (int i = tid; i < 64 * 64; i += 256) {
        int k = i >> 6, j = i & 63;
        Wl[i] = (j < 32) ? Wmu[k * 32 + j] : Wls[k * 32 + j - 32];
    }
    long rowbase = (long)blockIdx.x * 16;
    const float4* H4 = (const float4*)(h + rowbase * 64);
    float4* Hl4 = (float4*)Hl;
    for (int i = tid; i < 16 * 16; i += 256) Hl4[i] = H4[i];
    __syncthreads();
    int col = tid & 63, rg = tid >> 6;
    float acc[4] = {0.f, 0.f, 0.f, 0.f};
    for (int k = 0; k < 64; ++k) {
        float w = Wl[k * 64 + col];
#pragma unroll
        for (int i = 0; i < 4; ++i) acc[i] += Hl[(rg * 4 + i) * 64 + k] * w;
    }
#pragma unroll
    for (int i = 0; i < 4; ++i)
        t2[(rowbase + rg * 4 + i) * 64 + col] = (_Float16)acc[i];
}

// ---------------- fused gather-aggregations ----------------
// 2 nodes per wave (32 lanes each), lane covers dims 2*j2, 2*j2+1 via fp16x2
// loads.  Indices + dis prefetched lane-parallel, broadcast via __shfl(w=32).

// h[v] = l2normalize(relu(dis[v]*(sum_s dis[s]*t1[s] + dis[v]*t1[v]) + b1))
__global__ __launch_bounds__(256) void k_agg1(const half2v* __restrict__ tv,
                                              const int* __restrict__ row_ptr,
                                              const int* __restrict__ csr_src,
                                              const float* __restrict__ dis,
                                              const float* __restrict__ b1,
                                              float* __restrict__ h) {
    int lane = threadIdx.x & 63;
    int j2 = lane & 31;
    int v = blockIdx.x * 8 + (threadIdx.x >> 6) * 2 + (lane >> 5);   // NN = 12500*8
    int beg = row_ptr[v], end = row_ptr[v + 1];
    float acc0 = 0.f, acc1 = 0.f;
    for (int base = beg; base < end; base += 32) {
        int cnt = end - base; if (cnt > 32) cnt = 32;
        int idx = 0; float wgt = 0.f;
        if (j2 < cnt) { idx = csr_src[base + j2]; wgt = dis[idx]; }
        int k = 0;
        for (; k + 4 <= cnt; k += 4) {
            int s0 = __shfl(idx, k, 32), s1 = __shfl(idx, k + 1, 32),
                s2 = __shfl(idx, k + 2, 32), s3 = __shfl(idx, k + 3, 32);
            float w0 = __shfl(wgt, k, 32), w1 = __shfl(wgt, k + 1, 32),
                  w2 = __shfl(wgt, k + 2, 32), w3 = __shfl(wgt, k + 3, 32);
            half2v r0 = tv[s0 * 32 + j2];
            half2v r1 = tv[s1 * 32 + j2];
            half2v r2 = tv[s2 * 32 + j2];
            half2v r3 = tv[s3 * 32 + j2];
            acc0 += w0 * (float)r0.x; acc1 += w0 * (float)r0.y;
            acc0 += w1 * (float)r1.x; acc1 += w1 * (float)r1.y;
            acc0 += w2 * (float)r2.x; acc1 += w2 * (float)r2.y;
            acc0 += w3 * (float)r3.x; acc1 += w3 * (float)r3.y;
        }
        for (; k < cnt; ++k) {
            int s = __shfl(idx, k, 32);
            float w = __shfl(wgt, k, 32);
            half2v r = tv[s * 32 + j2];
            acc0 += w * (float)r.x; acc1 += w * (float)r.y;
        }
    }
    float dv = dis[v];
    half2v rv = tv[v * 32 + j2];
    float val0 = dv * (acc0 + dv * (float)rv.x) + b1[2 * j2];
    float val1 = dv * (acc1 + dv * (float)rv.y) + b1[2 * j2 + 1];
    val0 = fmaxf(val0, 0.0f);
    val1 = fmaxf(val1, 0.0f);
    float ss = val0 * val0 + val1 * val1;
#pragma unroll
    for (int m = 1; m < 32; m <<= 1) ss += __shfl_xor(ss, m);
    float scale = 1.0f / fmaxf(sqrtf(ss), 1e-12f);
    float2* h2 = (float2*)h;
    h2[v * 32 + j2] = make_float2(val0 * scale, val1 * scale);
}

// layer-2 aggregation fused with bias + reparametrize; writes mu, ls (f32), z (fp16)
__global__ __launch_bounds__(256) void k_agg2(const half2v* __restrict__ tv,
                                              const int* __restrict__ row_ptr,
                                              const int* __restrict__ csr_src,
                                              const float* __restrict__ dis,
                                              const float* __restrict__ bmu,
                                              const float* __restrict__ bls,
                                              const float* __restrict__ eps,
                                              float* __restrict__ mu,
                                              float* __restrict__ ls,
                                              _Float16* __restrict__ zh) {
    int lane = threadIdx.x & 63;
    int j2 = lane & 31;
    int v = blockIdx.x * 8 + (threadIdx.x >> 6) * 2 + (lane >> 5);
    int beg = row_ptr[v], end = row_ptr[v + 1];
    float acc0 = 0.f, acc1 = 0.f;
    for (int base = beg; base < end; base += 32) {
        int cnt = end - base; if (cnt > 32) cnt = 32;
        int idx = 0; float wgt = 0.f;
        if (j2 < cnt) { idx = csr_src[base + j2]; wgt = dis[idx]; }
        int k = 0;
        for (; k + 4 <= cnt; k += 4) {
            int s0 = __shfl(idx, k, 32), s1 = __shfl(idx, k + 1, 32),
                s2 = __shfl(idx, k + 2, 32), s3 = __shfl(idx, k + 3, 32);
            float w0 = __shfl(wgt, k, 32), w1 = __shfl(wgt, k + 1, 32),
                  w2 = __shfl(wgt, k + 2, 32), w3 = __shfl(wgt, k + 3, 32);
            half2v r0 = tv[s0 * 32 + j2];
            half2v r1 = tv[s1 * 32 + j2];
            half2v r2 = tv[s2 * 32 + j2];
            half2v r3 = tv[s3 * 32 + j2];
            acc0 += w0 * (float)r0.x; acc1 += w0 * (float)r0.y;
            acc0 += w1 * (float)r1.x; acc1 += w1 * (float)r1.y;
            acc0 += w2 * (float)r2.x; acc1 += w2 * (float)r2.y;
            acc0 += w3 * (float)r3.x; acc1 += w3 * (float)r3.y;
        }
        for (; k < cnt; ++k) {
            int s = __shfl(idx, k, 32);
            float w = __shfl(wgt, k, 32);
            half2v r = tv[s * 32 + j2];
            acc0 += w * (float)r.x; acc1 += w * (float)r.y;
        }
    }
    float dv = dis[v];
    half2v rv = tv[v * 32 + j2];
    // dims 2*j2, 2*j2+1: j2<16 -> mu dims, j2>=16 -> logstd dims
    float bb0 = (j2 < 16) ? bmu[2 * j2]     : bls[2 * j2 - 32];
    float bb1 = (j2 < 16) ? bmu[2 * j2 + 1] : bls[2 * j2 - 31];
    float val0 = dv * (acc0 + dv * (float)rv.x) + bb0;
    float val1 = dv * (acc1 + dv * (float)rv.y) + bb1;
    // lane j2 (<16) holds mu dims (2j2,2j2+1); lane j2+16 holds ls of same dims
    float o0 = __shfl_xor(val0, 16);
    float o1 = __shfl_xor(val1, 16);
    float2* mu2 = (float2*)mu;
    float2* ls2 = (float2*)ls;
    half2v* z2  = (half2v*)zh;
    const float2* e2 = (const float2*)eps;
    if (j2 < 16) {
        mu2[v * 16 + j2] = make_float2(val0, val1);
        float2 ev = e2[v * 16 + j2];
        float l0 = fminf(fmaxf(o0, -10.0f), 10.0f);
        float l1 = fminf(fmaxf(o1, -10.0f), 10.0f);
        half2v zw;
        zw.x = (_Float16)(val0 + ev.x * expf(l0));
        zw.y = (_Float16)(val1 + ev.y * expf(l1));
        z2[v * 16 + j2] = zw;
    } else {
        ls2[v * 16 + (j2 - 16)] = make_float2(val0, val1);
    }
}

// adj_pred[e] = sigmoid(<z[src], z[dst]>); z fp16 (row = 64 B = 1 line),
// 4 lanes per edge, 16 B loads
__global__ __launch_bounds__(256) void k_decode(const _Float16* __restrict__ zh,
                                                const int* __restrict__ src,
                                                const int* __restrict__ dst,
                                                float* __restrict__ out) {
    long t = (long)blockIdx.x * 256 + threadIdx.x;
    long e = t >> 2; int l = (int)(t & 3);
    if (e >= NE) return;
    int s = src[e], d = dst[e];
    const half8v* z8 = (const half8v*)zh;
    half8v a = z8[s * 4 + l];
    half8v b = z8[d * 4 + l];
    float p = 0.f;
#pragma unroll
    for (int i = 0; i < 8; ++i) p += (float)a[i] * (float)b[i];
    p += __shfl_xor(p, 1);
    p += __shfl_xor(p, 2);
    if (l == 0) out[e] = 1.0f / (1.0f + expf(-p));
}

extern "C" void kernel_launch(void* const* d_in, const int* in_sizes, int n_in,
                              void* d_out, int out_size, void* d_ws, size_t ws_size,
                              hipStream_t stream) {
    const float* x   = (const float*)d_in[0];
    const int*   ei  = (const int*)d_in[1];
    const float* eps = (const float*)d_in[2];
    const float* W1  = (const float*)d_in[3];
    const float* b1  = (const float*)d_in[4];
    const float* Wmu = (const float*)d_in[5];
    const float* bmu = (const float*)d_in[6];
    const float* Wls = (const float*)d_in[7];
    const float* bls = (const float*)d_in[8];
    const int* src = ei;        // edge_index[0]
    const int* dst = ei + NE;   // edge_index[1]

    float* out = (float*)d_out;
    float* adj = out;                       // [E]
    float* mu  = out + NE;                  // [N,32]
    float* ls  = mu + (long)NN * 32;        // [N,32]

    // workspace layout (all block byte sizes multiples of 16; z padded to 64B align)
    float* dis     = (float*)d_ws;              // NN
    int*   row_ptr = (int*)(dis + NN);          // 100004
    int*   hist    = row_ptr + 100004;          // NN
    int*   partial = hist + NN;                 // 512
    int*   counts  = partial + 512;             // NT*NB_BKT = 76636 -> pad 76640
    int*   ebuf    = counts + 76640;            // NE
    int*   csr_src = ebuf + NE;                 // NE
    _Float16* t    = (_Float16*)(csr_src + NE); // NN*64 fp16 (t1 then t2)
    float* h       = (float*)(t + (long)NN * 64);         // NN*64 f32
    _Float16* zh   = (_Float16*)(h + (long)NN * 64 + 12); // NN*32 fp16, 64B-aligned

    const int B = 256;
    const int NB_N = (NN + B - 1) / B;          // 391
    const int NB_E = (NE + B - 1) / B;          // 6250

    hipMemsetAsync(hist, 0, (size_t)NN * sizeof(int), stream);

    // CSR build + dis (no contended global atomics)
    k_hist <<<NB_E, B, 0, stream>>>(dst, hist);
    k_dis  <<<NB_N, B, 0, stream>>>(hist, dis);
    k_scan1<<<NB_N, B, 0, stream>>>(hist, row_ptr, partial);
    k_scan2<<<1, 512, 0, stream>>>(partial, NB_N);
    k_scan3<<<NB_N, B, 0, stream>>>(row_ptr, partial);
    k_cnt  <<<NT, B, 0, stream>>>(dst, counts);
    k_offs <<<(NB_BKT + B - 1) / B, B, 0, stream>>>(row_ptr, counts);
    k_place<<<NT, B, 0, stream>>>(src, dst, counts, ebuf);
    k_fill_b<<<NB_BKT, B, 0, stream>>>(row_ptr, ebuf, csr_src);

    // layer 1
    k_gemm1<<<NN / 16, B, 0, stream>>>(x, W1, t);
    k_agg1 <<<NN / 8, B, 0, stream>>>((const half2v*)t, row_ptr, csr_src, dis, b1, h);

    // layer 2
    k_gemm2<<<NN / 16, B, 0, stream>>>(h, Wmu, Wls, t);
    k_agg2 <<<NN / 8, B, 0, stream>>>((const half2v*)t, row_ptr, csr_src, dis,
                                      bmu, bls, eps, mu, ls, zh);

    // decode
    k_decode<<<(int)(((long)NE * 4 + B - 1) / B), B, 0, stream>>>(zh, src, dst, adj);
}

// Round 8
// 401.319 us; speedup vs baseline: 2.2667x; 1.1329x over previous
//
#include <hip/hip_runtime.h>
#include <hip/hip_fp16.h>

#define NN 100000
#define NE 1600000
#define W_BKT 128
#define NB_BKT ((NN + W_BKT - 1) / W_BKT)   // 782
#define TILE_E 16384                         // edges per counting-sort tile
#define NT ((NE + TILE_E - 1) / TILE_E)      // 98
#define STAGE_CAP 4352                       // LDS staging (avg bucket ~2048, sigma ~45)
// IN=128, HID=64, OUT=32

typedef _Float16 half2v __attribute__((ext_vector_type(2)));
typedef _Float16 half8v __attribute__((ext_vector_type(8)));

// ---- deterministic two-pass bucket sort + fused CSR/deg build (NO global atomics) ----

// per-tile bucket histogram via LDS atomics
__global__ __launch_bounds__(256) void k_cnt(const int* __restrict__ dst,
                                             int* __restrict__ counts) {
    __shared__ int hc[NB_BKT];
    int tid = threadIdx.x;
    for (int i = tid; i < NB_BKT; i += 256) hc[i] = 0;
    __syncthreads();
    int base = blockIdx.x * TILE_E;
    int lim = base + TILE_E; if (lim > NE) lim = NE;
    for (int e = base + tid; e < lim; e += 256)
        atomicAdd(&hc[dst[e] >> 7], 1);
    __syncthreads();
    for (int i = tid; i < NB_BKT; i += 256)
        counts[blockIdx.x * NB_BKT + i] = hc[i];
}

// bucket totals + exclusive scan -> bucket_base[0..NB_BKT]
__global__ __launch_bounds__(1024) void k_bscan(const int* __restrict__ counts,
                                                int* __restrict__ bucket_base) {
    __shared__ int buf[1024];
    int tid = threadIdx.x;
    int total = 0;
    if (tid < NB_BKT)
        for (int t = 0; t < NT; ++t) total += counts[t * NB_BKT + tid];
    buf[tid] = total;
    __syncthreads();
    for (int off = 1; off < 1024; off <<= 1) {
        int v = (tid >= off) ? buf[tid - off] : 0;
        __syncthreads();
        buf[tid] += v;
        __syncthreads();
    }
    if (tid < NB_BKT) bucket_base[tid] = buf[tid] - total;   // exclusive
    if (tid == 0) bucket_base[NB_BKT] = NE;
}

// per-(tile,bucket) base offsets: running sum over tiles seeded from bucket_base
__global__ __launch_bounds__(256) void k_offs(const int* __restrict__ bucket_base,
                                              int* __restrict__ counts) {
    int b = blockIdx.x * 256 + threadIdx.x;
    if (b >= NB_BKT) return;
    int off = bucket_base[b];
    for (int t = 0; t < NT; ++t) {
        int c = counts[t * NB_BKT + b];
        counts[t * NB_BKT + b] = off;
        off += c;
    }
}

// re-read tile, place packed (src<<7 | d&127) at deterministic positions
__global__ __launch_bounds__(256) void k_place(const int* __restrict__ src,
                                               const int* __restrict__ dst,
                                               const int* __restrict__ counts,
                                               int* __restrict__ ebuf) {
    __shared__ int cur[NB_BKT];
    int tid = threadIdx.x;
    for (int i = tid; i < NB_BKT; i += 256)
        cur[i] = counts[blockIdx.x * NB_BKT + i];
    __syncthreads();
    int base = blockIdx.x * TILE_E;
    int lim = base + TILE_E; if (lim > NE) lim = NE;
    for (int e = base + tid; e < lim; e += 256) {
        int s = src[e], d = dst[e];
        int pos = atomicAdd(&cur[d >> 7], 1);     // LDS atomic, ~21/counter
        ebuf[pos] = (s << 7) | (d & 127);
    }
}

// one block per bucket: LDS-stage the bucket's ebuf slice, count 128 node degs,
// prefix-scan -> row_ptr + dis, then scatter to csr_src.  Replaces
// k_hist/k_dis/k_scan1-3/k_fill_b with zero global atomics.
__global__ __launch_bounds__(256) void k_build(const int* __restrict__ bucket_base,
                                               const int* __restrict__ ebuf,
                                               int* __restrict__ csr_src,
                                               int* __restrict__ row_ptr,
                                               float* __restrict__ dis) {
    __shared__ int deg[W_BKT];
    __shared__ int pre[W_BKT];
    __shared__ int cur[W_BKT];
    __shared__ int stage[STAGE_CAP];
    int b = blockIdx.x;
    int tid = threadIdx.x;
    int beg = bucket_base[b], end = bucket_base[b + 1];
    int n = end - beg;
    if (tid < W_BKT) deg[tid] = 0;
    __syncthreads();
    bool fits = (n <= STAGE_CAP);
    if (fits) {
        for (int i = tid; i < n; i += 256) {
            int val = ebuf[beg + i];
            stage[i] = val;
            atomicAdd(&deg[val & 127], 1);
        }
    } else {
        for (int i = tid; i < n; i += 256)
            atomicAdd(&deg[ebuf[beg + i] & 127], 1);
    }
    __syncthreads();
    if (tid < W_BKT) pre[tid] = deg[tid];
    __syncthreads();
    for (int off = 1; off < W_BKT; off <<= 1) {
        int v = (tid >= off && tid < W_BKT) ? pre[tid - off] : 0;
        __syncthreads();
        if (tid < W_BKT) pre[tid] += v;
        __syncthreads();
    }
    if (tid < W_BKT) {
        int v = b * W_BKT + tid;
        int rp = beg + pre[tid] - deg[tid];      // exclusive prefix
        if (v < NN) {
            row_ptr[v] = rp;
            dis[v] = rsqrtf((float)(1 + deg[tid]));
        }
        cur[tid] = rp;
    }
    if (b == NB_BKT - 1 && tid == 0) row_ptr[NN] = NE;
    __syncthreads();
    if (fits) {
        for (int i = tid; i < n; i += 256) {
            int val = stage[i];
            int pos = atomicAdd(&cur[val & 127], 1);
            csr_src[pos] = val >> 7;
        }
    } else {
        for (int i = tid; i < n; i += 256) {
            int val = ebuf[beg + i];
            int pos = atomicAdd(&cur[val & 127], 1);
            csr_src[pos] = val >> 7;
        }
    }
}

// ---------------- dense transforms ----------------

// t1[N,64] = x[N,128] @ W1[128,64], stored fp16.  16 rows/block, W1+x in LDS.
__global__ __launch_bounds__(256) void k_gemm1(const float* __restrict__ x,
                                               const float* __restrict__ W1,
                                               _Float16* __restrict__ t1) {
    __shared__ float Wl[128 * 64];
    __shared__ float Xl[16 * 128];
    int tid = threadIdx.x;
    const float4* W4 = (const float4*)W1;
    float4* Wl4 = (float4*)Wl;
    for (int i = tid; i < 128 * 16; i += 256) Wl4[i] = W4[i];
    long rowbase = (long)blockIdx.x * 16;      // N = 6250 * 16 exactly
    const float4* X4 = (const float4*)(x + rowbase * 128);
    float4* Xl4 = (float4*)Xl;
    for (int i = tid; i < 16 * 32; i += 256) Xl4[i] = X4[i];
    __syncthreads();
    int col = tid & 63, rg = tid >> 6;
    float acc[4] = {0.f, 0.f, 0.f, 0.f};
    for (int k = 0; k < 128; ++k) {
        float w = Wl[k * 64 + col];
#pragma unroll
        for (int i = 0; i < 4; ++i) acc[i] += Xl[(rg * 4 + i) * 128 + k] * w;
    }
#pragma unroll
    for (int i = 0; i < 4; ++i)
        t1[(rowbase + rg * 4 + i) * 64 + col] = (_Float16)acc[i];
}

// t2[N,64] = h[N,64] @ [Wmu | Wls]  (each [64,32]), stored fp16
__global__ __launch_bounds__(256) void k_gemm2(const float* __restrict__ h,
                                               const float* __restrict__ Wmu,
                                               const float* __restrict__ Wls,
                                               _Float16* __restrict__ t2) {
    __shared__ float Wl[64 * 64];
    __shared__ float Hl[16 * 64];
    int tid = threadIdx.x;
    for (int i = tid; i < 64 * 64; i += 256) {
        int k = i >> 6, j = i & 63;
        Wl[i] = (j < 32) ? Wmu[k * 32 + j] : Wls[k * 32 + j - 32];
    }
    long rowbase = (long)blockIdx.x * 16;
    const float4* H4 = (const float4*)(h + rowbase * 64);
    float4* Hl4 = (float4*)Hl;
    for (int i = tid; i < 16 * 16; i += 256) Hl4[i] = H4[i];
    __syncthreads();
    int col = tid & 63, rg = tid >> 6;
    float acc[4] = {0.f, 0.f, 0.f, 0.f};
    for (int k = 0; k < 64; ++k) {
        float w = Wl[k * 64 + col];
#pragma unroll
        for (int i = 0; i < 4; ++i) acc[i] += Hl[(rg * 4 + i) * 64 + k] * w;
    }
#pragma unroll
    for (int i = 0; i < 4; ++i)
        t2[(rowbase + rg * 4 + i) * 64 + col] = (_Float16)acc[i];
}

// ---------------- fused gather-aggregations ----------------
// 2 nodes per wave (32 lanes each), lane covers dims 2*j2, 2*j2+1 via fp16x2
// loads.  Indices + dis prefetched lane-parallel, broadcast via __shfl(w=32).

// h[v] = l2normalize(relu(dis[v]*(sum_s dis[s]*t1[s] + dis[v]*t1[v]) + b1))
__global__ __launch_bounds__(256) void k_agg1(const half2v* __restrict__ tv,
                                              const int* __restrict__ row_ptr,
                                              const int* __restrict__ csr_src,
                                              const float* __restrict__ dis,
                                              const float* __restrict__ b1,
                                              float* __restrict__ h) {
    int lane = threadIdx.x & 63;
    int j2 = lane & 31;
    int v = blockIdx.x * 8 + (threadIdx.x >> 6) * 2 + (lane >> 5);   // NN = 12500*8
    int beg = row_ptr[v], end = row_ptr[v + 1];
    float acc0 = 0.f, acc1 = 0.f;
    for (int base = beg; base < end; base += 32) {
        int cnt = end - base; if (cnt > 32) cnt = 32;
        int idx = 0; float wgt = 0.f;
        if (j2 < cnt) { idx = csr_src[base + j2]; wgt = dis[idx]; }
        int k = 0;
        for (; k + 4 <= cnt; k += 4) {
            int s0 = __shfl(idx, k, 32), s1 = __shfl(idx, k + 1, 32),
                s2 = __shfl(idx, k + 2, 32), s3 = __shfl(idx, k + 3, 32);
            float w0 = __shfl(wgt, k, 32), w1 = __shfl(wgt, k + 1, 32),
                  w2 = __shfl(wgt, k + 2, 32), w3 = __shfl(wgt, k + 3, 32);
            half2v r0 = tv[s0 * 32 + j2];
            half2v r1 = tv[s1 * 32 + j2];
            half2v r2 = tv[s2 * 32 + j2];
            half2v r3 = tv[s3 * 32 + j2];
            acc0 += w0 * (float)r0.x; acc1 += w0 * (float)r0.y;
            acc0 += w1 * (float)r1.x; acc1 += w1 * (float)r1.y;
            acc0 += w2 * (float)r2.x; acc1 += w2 * (float)r2.y;
            acc0 += w3 * (float)r3.x; acc1 += w3 * (float)r3.y;
        }
        for (; k < cnt; ++k) {
            int s = __shfl(idx, k, 32);
            float w = __shfl(wgt, k, 32);
            half2v r = tv[s * 32 + j2];
            acc0 += w * (float)r.x; acc1 += w * (float)r.y;
        }
    }
    float dv = dis[v];
    half2v rv = tv[v * 32 + j2];
    float val0 = dv * (acc0 + dv * (float)rv.x) + b1[2 * j2];
    float val1 = dv * (acc1 + dv * (float)rv.y) + b1[2 * j2 + 1];
    val0 = fmaxf(val0, 0.0f);
    val1 = fmaxf(val1, 0.0f);
    float ss = val0 * val0 + val1 * val1;
#pragma unroll
    for (int m = 1; m < 32; m <<= 1) ss += __shfl_xor(ss, m);
    float scale = 1.0f / fmaxf(sqrtf(ss), 1e-12f);
    float2* h2 = (float2*)h;
    h2[v * 32 + j2] = make_float2(val0 * scale, val1 * scale);
}

// layer-2 aggregation fused with bias + reparametrize; writes mu, ls (f32), z (fp16)
__global__ __launch_bounds__(256) void k_agg2(const half2v* __restrict__ tv,
                                              const int* __restrict__ row_ptr,
                                              const int* __restrict__ csr_src,
                                              const float* __restrict__ dis,
                                              const float* __restrict__ bmu,
                                              const float* __restrict__ bls,
                                              const float* __restrict__ eps,
                                              float* __restrict__ mu,
                                              float* __restrict__ ls,
                                              _Float16* __restrict__ zh) {
    int lane = threadIdx.x & 63;
    int j2 = lane & 31;
    int v = blockIdx.x * 8 + (threadIdx.x >> 6) * 2 + (lane >> 5);
    int beg = row_ptr[v], end = row_ptr[v + 1];
    float acc0 = 0.f, acc1 = 0.f;
    for (int base = beg; base < end; base += 32) {
        int cnt = end - base; if (cnt > 32) cnt = 32;
        int idx = 0; float wgt = 0.f;
        if (j2 < cnt) { idx = csr_src[base + j2]; wgt = dis[idx]; }
        int k = 0;
        for (; k + 4 <= cnt; k += 4) {
            int s0 = __shfl(idx, k, 32), s1 = __shfl(idx, k + 1, 32),
                s2 = __shfl(idx, k + 2, 32), s3 = __shfl(idx, k + 3, 32);
            float w0 = __shfl(wgt, k, 32), w1 = __shfl(wgt, k + 1, 32),
                  w2 = __shfl(wgt, k + 2, 32), w3 = __shfl(wgt, k + 3, 32);
            half2v r0 = tv[s0 * 32 + j2];
            half2v r1 = tv[s1 * 32 + j2];
            half2v r2 = tv[s2 * 32 + j2];
            half2v r3 = tv[s3 * 32 + j2];
            acc0 += w0 * (float)r0.x; acc1 += w0 * (float)r0.y;
            acc0 += w1 * (float)r1.x; acc1 += w1 * (float)r1.y;
            acc0 += w2 * (float)r2.x; acc1 += w2 * (float)r2.y;
            acc0 += w3 * (float)r3.x; acc1 += w3 * (float)r3.y;
        }
        for (; k < cnt; ++k) {
            int s = __shfl(idx, k, 32);
            float w = __shfl(wgt, k, 32);
            half2v r = tv[s * 32 + j2];
            acc0 += w * (float)r.x; acc1 += w * (float)r.y;
        }
    }
    float dv = dis[v];
    half2v rv = tv[v * 32 + j2];
    // dims 2*j2, 2*j2+1: j2<16 -> mu dims, j2>=16 -> logstd dims
    float bb0 = (j2 < 16) ? bmu[2 * j2]     : bls[2 * j2 - 32];
    float bb1 = (j2 < 16) ? bmu[2 * j2 + 1] : bls[2 * j2 - 31];
    float val0 = dv * (acc0 + dv * (float)rv.x) + bb0;
    float val1 = dv * (acc1 + dv * (float)rv.y) + bb1;
    // lane j2 (<16) holds mu dims (2j2,2j2+1); lane j2+16 holds ls of same dims
    float o0 = __shfl_xor(val0, 16);
    float o1 = __shfl_xor(val1, 16);
    float2* mu2 = (float2*)mu;
    float2* ls2 = (float2*)ls;
    half2v* z2  = (half2v*)zh;
    const float2* e2 = (const float2*)eps;
    if (j2 < 16) {
        mu2[v * 16 + j2] = make_float2(val0, val1);
        float2 ev = e2[v * 16 + j2];
        float l0 = fminf(fmaxf(o0, -10.0f), 10.0f);
        float l1 = fminf(fmaxf(o1, -10.0f), 10.0f);
        half2v zw;
        zw.x = (_Float16)(val0 + ev.x * expf(l0));
        zw.y = (_Float16)(val1 + ev.y * expf(l1));
        z2[v * 16 + j2] = zw;
    } else {
        ls2[v * 16 + (j2 - 16)] = make_float2(val0, val1);
    }
}

// adj_pred[e] = sigmoid(<z[src], z[dst]>); z fp16 (row = 64 B = 1 line),
// 4 lanes per edge, 16 B loads
__global__ __launch_bounds__(256) void k_decode(const _Float16* __restrict__ zh,
                                                const int* __restrict__ src,
                                                const int* __restrict__ dst,
                                                float* __restrict__ out) {
    long t = (long)blockIdx.x * 256 + threadIdx.x;
    long e = t >> 2; int l = (int)(t & 3);
    if (e >= NE) return;
    int s = src[e], d = dst[e];
    const half8v* z8 = (const half8v*)zh;
    half8v a = z8[s * 4 + l];
    half8v b = z8[d * 4 + l];
    float p = 0.f;
#pragma unroll
    for (int i = 0; i < 8; ++i) p += (float)a[i] * (float)b[i];
    p += __shfl_xor(p, 1);
    p += __shfl_xor(p, 2);
    if (l == 0) out[e] = 1.0f / (1.0f + expf(-p));
}

extern "C" void kernel_launch(void* const* d_in, const int* in_sizes, int n_in,
                              void* d_out, int out_size, void* d_ws, size_t ws_size,
                              hipStream_t stream) {
    const float* x   = (const float*)d_in[0];
    const int*   ei  = (const int*)d_in[1];
    const float* eps = (const float*)d_in[2];
    const float* W1  = (const float*)d_in[3];
    const float* b1  = (const float*)d_in[4];
    const float* Wmu = (const float*)d_in[5];
    const float* bmu = (const float*)d_in[6];
    const float* Wls = (const float*)d_in[7];
    const float* bls = (const float*)d_in[8];
    const int* src = ei;        // edge_index[0]
    const int* dst = ei + NE;   // edge_index[1]

    float* out = (float*)d_out;
    float* adj = out;                       // [E]
    float* mu  = out + NE;                  // [N,32]
    float* ls  = mu + (long)NN * 32;        // [N,32]

    // workspace layout (all block byte sizes multiples of 16; z 64B-aligned)
    float* dis      = (float*)d_ws;              // NN
    int*   row_ptr  = (int*)(dis + NN);          // 100004
    int*   bucket_base = row_ptr + 100004;       // NB_BKT+1 -> pad 784
    int*   counts   = bucket_base + 784;         // NT*NB_BKT = 76636 -> pad 76640
    int*   ebuf     = counts + 76640;            // NE
    int*   csr_src  = ebuf + NE;                 // NE
    _Float16* t     = (_Float16*)(csr_src + NE); // NN*64 fp16 (t1 then t2)
    float* h        = (float*)(t + (long)NN * 64);         // NN*64 f32
    _Float16* zh    = (_Float16*)(h + (long)NN * 64 + 12); // NN*32 fp16, 64B-aligned

    const int B = 256;

    // CSR + deg/dis build — zero global atomics
    k_cnt  <<<NT, B, 0, stream>>>(dst, counts);
    k_bscan<<<1, 1024, 0, stream>>>(counts, bucket_base);
    k_offs <<<(NB_BKT + B - 1) / B, B, 0, stream>>>(bucket_base, counts);
    k_place<<<NT, B, 0, stream>>>(src, dst, counts, ebuf);
    k_build<<<NB_BKT, B, 0, stream>>>(bucket_base, ebuf, csr_src, row_ptr, dis);

    // layer 1
    k_gemm1<<<NN / 16, B, 0, stream>>>(x, W1, t);
    k_agg1 <<<NN / 8, B, 0, stream>>>((const half2v*)t, row_ptr, csr_src, dis, b1, h);

    // layer 2
    k_gemm2<<<NN / 16, B, 0, stream>>>(h, Wmu, Wls, t);
    k_agg2 <<<NN / 8, B, 0, stream>>>((const half2v*)t, row_ptr, csr_src, dis,
                                      bmu, bls, eps, mu, ls, zh);

    // decode
    k_decode<<<(int)(((long)NE * 4 + B - 1) / B), B, 0, stream>>>(zh, src, dst, adj);
}

// Round 10
// 391.455 us; speedup vs baseline: 2.3238x; 1.0252x over previous
//
#include <hip/hip_runtime.h>
#include <hip/hip_fp16.h>

#define NN 100000
#define NE 1600000
#define W_BKT 128
#define NB_BKT ((NN + W_BKT - 1) / W_BKT)   // 782
#define TILE_E 16384                         // edges per counting-sort tile
#define NT ((NE + TILE_E - 1) / TILE_E)      // 98
#define STAGE_CAP 4352                       // LDS staging (avg bucket ~2048)
// IN=128, HID=64, OUT=32

typedef _Float16 half2v __attribute__((ext_vector_type(2)));
typedef _Float16 half8v __attribute__((ext_vector_type(8)));
typedef float float2v __attribute__((ext_vector_type(2)));

// ---- deterministic two-pass bucket sort + fused CSR/deg build (NO global atomics) ----

__global__ __launch_bounds__(256) void k_cnt(const int* __restrict__ dst,
                                             int* __restrict__ counts) {
    __shared__ int hc[NB_BKT];
    int tid = threadIdx.x;
    for (int i = tid; i < NB_BKT; i += 256) hc[i] = 0;
    __syncthreads();
    int base = blockIdx.x * TILE_E;
    int lim = base + TILE_E; if (lim > NE) lim = NE;
    for (int e = base + tid; e < lim; e += 256)
        atomicAdd(&hc[dst[e] >> 7], 1);
    __syncthreads();
    for (int i = tid; i < NB_BKT; i += 256)
        counts[blockIdx.x * NB_BKT + i] = hc[i];
}

__global__ __launch_bounds__(1024) void k_bscan(const int* __restrict__ counts,
                                                int* __restrict__ bucket_base) {
    __shared__ int buf[1024];
    int tid = threadIdx.x;
    int total = 0;
    if (tid < NB_BKT)
        for (int t = 0; t < NT; ++t) total += counts[t * NB_BKT + tid];
    buf[tid] = total;
    __syncthreads();
    for (int off = 1; off < 1024; off <<= 1) {
        int v = (tid >= off) ? buf[tid - off] : 0;
        __syncthreads();
        buf[tid] += v;
        __syncthreads();
    }
    if (tid < NB_BKT) bucket_base[tid] = buf[tid] - total;   // exclusive
    if (tid == 0) bucket_base[NB_BKT] = NE;
}

__global__ __launch_bounds__(256) void k_offs(const int* __restrict__ bucket_base,
                                              int* __restrict__ counts) {
    int b = blockIdx.x * 256 + threadIdx.x;
    if (b >= NB_BKT) return;
    int off = bucket_base[b];
    for (int t = 0; t < NT; ++t) {
        int c = counts[t * NB_BKT + b];
        counts[t * NB_BKT + b] = off;
        off += c;
    }
}

__global__ __launch_bounds__(256) void k_place(const int* __restrict__ src,
                                               const int* __restrict__ dst,
                                               const int* __restrict__ counts,
                                               int* __restrict__ ebuf) {
    __shared__ int cur[NB_BKT];
    int tid = threadIdx.x;
    for (int i = tid; i < NB_BKT; i += 256)
        cur[i] = counts[blockIdx.x * NB_BKT + i];
    __syncthreads();
    int base = blockIdx.x * TILE_E;
    int lim = base + TILE_E; if (lim > NE) lim = NE;
    for (int e = base + tid; e < lim; e += 256) {
        int s = src[e], d = dst[e];
        int pos = atomicAdd(&cur[d >> 7], 1);     // LDS atomic, ~21/counter
        ebuf[pos] = (s << 7) | (d & 127);
    }
}

// one block per bucket: LDS-stage the bucket's ebuf slice, count 128 node degs,
// prefix-scan -> row_ptr + dis, then scatter to csr_src.
__global__ __launch_bounds__(256) void k_build(const int* __restrict__ bucket_base,
                                               const int* __restrict__ ebuf,
                                               int* __restrict__ csr_src,
                                               int* __restrict__ row_ptr,
                                               float* __restrict__ dis) {
    __shared__ int deg[W_BKT];
    __shared__ int pre[W_BKT];
    __shared__ int cur[W_BKT];
    __shared__ int stage[STAGE_CAP];
    int b = blockIdx.x;
    int tid = threadIdx.x;
    int beg = bucket_base[b], end = bucket_base[b + 1];
    int n = end - beg;
    if (tid < W_BKT) deg[tid] = 0;
    __syncthreads();
    bool fits = (n <= STAGE_CAP);
    if (fits) {
        for (int i = tid; i < n; i += 256) {
            int val = ebuf[beg + i];
            stage[i] = val;
            atomicAdd(&deg[val & 127], 1);
        }
    } else {
        for (int i = tid; i < n; i += 256)
            atomicAdd(&deg[ebuf[beg + i] & 127], 1);
    }
    __syncthreads();
    if (tid < W_BKT) pre[tid] = deg[tid];
    __syncthreads();
    for (int off = 1; off < W_BKT; off <<= 1) {
        int v = (tid >= off && tid < W_BKT) ? pre[tid - off] : 0;
        __syncthreads();
        if (tid < W_BKT) pre[tid] += v;
        __syncthreads();
    }
    if (tid < W_BKT) {
        int v = b * W_BKT + tid;
        int rp = beg + pre[tid] - deg[tid];      // exclusive prefix
        if (v < NN) {
            row_ptr[v] = rp;
            dis[v] = rsqrtf((float)(1 + deg[tid]));
        }
        cur[tid] = rp;
    }
    if (b == NB_BKT - 1 && tid == 0) row_ptr[NN] = NE;
    __syncthreads();
    if (fits) {
        for (int i = tid; i < n; i += 256) {
            int val = stage[i];
            int pos = atomicAdd(&cur[val & 127], 1);
            csr_src[pos] = val >> 7;
        }
    } else {
        for (int i = tid; i < n; i += 256) {
            int val = ebuf[beg + i];
            int pos = atomicAdd(&cur[val & 127], 1);
            csr_src[pos] = val >> 7;
        }
    }
}

// ---------------- dense transforms (dis folded into stored rows) ----------------

// t1'[v] = dis[v] * (x[v] @ W1), stored fp16.  16 rows/block, W1+x in LDS.
__global__ __launch_bounds__(256) void k_gemm1(const float* __restrict__ x,
                                               const float* __restrict__ W1,
                                               const float* __restrict__ dis,
                                               _Float16* __restrict__ t1) {
    __shared__ float Wl[128 * 64];
    __shared__ float Xl[16 * 128];
    int tid = threadIdx.x;
    const float4* W4 = (const float4*)W1;
    float4* Wl4 = (float4*)Wl;
    for (int i = tid; i < 128 * 16; i += 256) Wl4[i] = W4[i];
    long rowbase = (long)blockIdx.x * 16;      // N = 6250 * 16 exactly
    const float4* X4 = (const float4*)(x + rowbase * 128);
    float4* Xl4 = (float4*)Xl;
    for (int i = tid; i < 16 * 32; i += 256) Xl4[i] = X4[i];
    __syncthreads();
    int col = tid & 63, rg = tid >> 6;
    float acc[4] = {0.f, 0.f, 0.f, 0.f};
    for (int k = 0; k < 128; ++k) {
        float w = Wl[k * 64 + col];
#pragma unroll
        for (int i = 0; i < 4; ++i) acc[i] += Xl[(rg * 4 + i) * 128 + k] * w;
    }
#pragma unroll
    for (int i = 0; i < 4; ++i) {
        long row = rowbase + rg * 4 + i;
        t1[row * 64 + col] = (_Float16)(acc[i] * dis[row]);
    }
}

// t2'[v] = dis[v] * (h[v] @ [Wmu | Wls]), stored fp16
__global__ __launch_bounds__(256) void k_gemm2(const float* __restrict__ h,
                                               const float* __restrict__ Wmu,
                                               const float* __restrict__ Wls,
                                               const float* __restrict__ dis,
                                               _Float16* __restrict__ t2) {
    __shared__ float Wl[64 * 64];
    __shared__ float Hl[16 * 64];
    int tid = threadIdx.x;
    for (int i = tid; i < 64 * 64; i += 256) {
        int k = i >> 6, j = i & 63;
        Wl[i] = (j < 32) ? Wmu[k * 32 + j] : Wls[k * 32 + j - 32];
    }
    long rowbase = (long)blockIdx.x * 16;
    const float4* H4 = (const float4*)(h + rowbase * 64);
    float4* Hl4 = (float4*)Hl;
    for (int i = tid; i < 16 * 16; i += 256) Hl4[i] = H4[i];
    __syncthreads();
    int col = tid & 63, rg = tid >> 6;
    float acc[4] = {0.f, 0.f, 0.f, 0.f};
    for (int k = 0; k < 64; ++k) {
        float w = Wl[k * 64 + col];
#pragma unroll
        for (int i = 0; i < 4; ++i) acc[i] += Hl[(rg * 4 + i) * 64 + k] * w;
    }
#pragma unroll
    for (int i = 0; i < 4; ++i) {
        long row = rowbase + rg * 4 + i;
        t2[row * 64 + col] = (_Float16)(acc[i] * dis[row]);
    }
}

// ---------------- fused gather-aggregations ----------------
// Tables pre-scaled by dis[src]: inner loop = shfl -> load -> cvt+add only.
// 2 nodes per wave (32 lanes each); lane covers dims 2*j2, 2*j2+1 (fp16x2).

// h[v] = l2normalize(relu(dis[v]*(sum_s t1'[s] + t1'[v]) + b1))
__global__ __launch_bounds__(256) void k_agg1(const half2v* __restrict__ tv,
                                              const int* __restrict__ row_ptr,
                                              const int* __restrict__ csr_src,
                                              const float* __restrict__ dis,
                                              const float* __restrict__ b1,
                                              float* __restrict__ h) {
    int lane = threadIdx.x & 63;
    int j2 = lane & 31;
    int v = blockIdx.x * 8 + (threadIdx.x >> 6) * 2 + (lane >> 5);   // NN = 12500*8
    int beg = row_ptr[v], end = row_ptr[v + 1];
    float acc0 = 0.f, acc1 = 0.f;
    for (int base = beg; base < end; base += 32) {
        int cnt = end - base; if (cnt > 32) cnt = 32;
        int idx = 0;
        if (j2 < cnt) idx = csr_src[base + j2];
        int k = 0;
        for (; k + 8 <= cnt; k += 8) {
            int s0 = __shfl(idx, k, 32),     s1 = __shfl(idx, k + 1, 32),
                s2 = __shfl(idx, k + 2, 32), s3 = __shfl(idx, k + 3, 32),
                s4 = __shfl(idx, k + 4, 32), s5 = __shfl(idx, k + 5, 32),
                s6 = __shfl(idx, k + 6, 32), s7 = __shfl(idx, k + 7, 32);
            half2v r0 = tv[s0 * 32 + j2];
            half2v r1 = tv[s1 * 32 + j2];
            half2v r2 = tv[s2 * 32 + j2];
            half2v r3 = tv[s3 * 32 + j2];
            half2v r4 = tv[s4 * 32 + j2];
            half2v r5 = tv[s5 * 32 + j2];
            half2v r6 = tv[s6 * 32 + j2];
            half2v r7 = tv[s7 * 32 + j2];
            acc0 += (float)r0.x; acc1 += (float)r0.y;
            acc0 += (float)r1.x; acc1 += (float)r1.y;
            acc0 += (float)r2.x; acc1 += (float)r2.y;
            acc0 += (float)r3.x; acc1 += (float)r3.y;
            acc0 += (float)r4.x; acc1 += (float)r4.y;
            acc0 += (float)r5.x; acc1 += (float)r5.y;
            acc0 += (float)r6.x; acc1 += (float)r6.y;
            acc0 += (float)r7.x; acc1 += (float)r7.y;
        }
        for (; k < cnt; ++k) {
            int s = __shfl(idx, k, 32);
            half2v r = tv[s * 32 + j2];
            acc0 += (float)r.x; acc1 += (float)r.y;
        }
    }
    float dv = dis[v];
    half2v rv = tv[v * 32 + j2];                 // = dis[v]*t1[v]
    float val0 = dv * (acc0 + (float)rv.x) + b1[2 * j2];
    float val1 = dv * (acc1 + (float)rv.y) + b1[2 * j2 + 1];
    val0 = fmaxf(val0, 0.0f);
    val1 = fmaxf(val1, 0.0f);
    float ss = val0 * val0 + val1 * val1;
#pragma unroll
    for (int m = 1; m < 32; m <<= 1) ss += __shfl_xor(ss, m);
    float scale = 1.0f / fmaxf(sqrtf(ss), 1e-12f);
    float2v* h2 = (float2v*)h;
    float2v hv; hv.x = val0 * scale; hv.y = val1 * scale;
    h2[v * 32 + j2] = hv;
}

// layer-2 aggregation fused with bias + reparametrize; writes mu, ls (f32), z (fp16)
__global__ __launch_bounds__(256) void k_agg2(const half2v* __restrict__ tv,
                                              const int* __restrict__ row_ptr,
                                              const int* __restrict__ csr_src,
                                              const float* __restrict__ dis,
                                              const float* __restrict__ bmu,
                                              const float* __restrict__ bls,
                                              const float* __restrict__ eps,
                                              float* __restrict__ mu,
                                              float* __restrict__ ls,
                                              _Float16* __restrict__ zh) {
    int lane = threadIdx.x & 63;
    int j2 = lane & 31;
    int v = blockIdx.x * 8 + (threadIdx.x >> 6) * 2 + (lane >> 5);
    int beg = row_ptr[v], end = row_ptr[v + 1];
    float acc0 = 0.f, acc1 = 0.f;
    for (int base = beg; base < end; base += 32) {
        int cnt = end - base; if (cnt > 32) cnt = 32;
        int idx = 0;
        if (j2 < cnt) idx = csr_src[base + j2];
        int k = 0;
        for (; k + 8 <= cnt; k += 8) {
            int s0 = __shfl(idx, k, 32),     s1 = __shfl(idx, k + 1, 32),
                s2 = __shfl(idx, k + 2, 32), s3 = __shfl(idx, k + 3, 32),
                s4 = __shfl(idx, k + 4, 32), s5 = __shfl(idx, k + 5, 32),
                s6 = __shfl(idx, k + 6, 32), s7 = __shfl(idx, k + 7, 32);
            half2v r0 = tv[s0 * 32 + j2];
            half2v r1 = tv[s1 * 32 + j2];
            half2v r2 = tv[s2 * 32 + j2];
            half2v r3 = tv[s3 * 32 + j2];
            half2v r4 = tv[s4 * 32 + j2];
            half2v r5 = tv[s5 * 32 + j2];
            half2v r6 = tv[s6 * 32 + j2];
            half2v r7 = tv[s7 * 32 + j2];
            acc0 += (float)r0.x; acc1 += (float)r0.y;
            acc0 += (float)r1.x; acc1 += (float)r1.y;
            acc0 += (float)r2.x; acc1 += (float)r2.y;
            acc0 += (float)r3.x; acc1 += (float)r3.y;
            acc0 += (float)r4.x; acc1 += (float)r4.y;
            acc0 += (float)r5.x; acc1 += (float)r5.y;
            acc0 += (float)r6.x; acc1 += (float)r6.y;
            acc0 += (float)r7.x; acc1 += (float)r7.y;
        }
        for (; k < cnt; ++k) {
            int s = __shfl(idx, k, 32);
            half2v r = tv[s * 32 + j2];
            acc0 += (float)r.x; acc1 += (float)r.y;
        }
    }
    float dv = dis[v];
    half2v rv = tv[v * 32 + j2];                 // = dis[v]*t2[v]
    float bb0 = (j2 < 16) ? bmu[2 * j2]     : bls[2 * j2 - 32];
    float bb1 = (j2 < 16) ? bmu[2 * j2 + 1] : bls[2 * j2 - 31];
    float val0 = dv * (acc0 + (float)rv.x) + bb0;
    float val1 = dv * (acc1 + (float)rv.y) + bb1;
    float o0 = __shfl_xor(val0, 16);
    float o1 = __shfl_xor(val1, 16);
    float2v* mu2 = (float2v*)mu;
    float2v* ls2 = (float2v*)ls;
    half2v* z2  = (half2v*)zh;
    const float2* e2 = (const float2*)eps;
    if (j2 < 16) {
        float2v mv; mv.x = val0; mv.y = val1;
        __builtin_nontemporal_store(mv, &mu2[v * 16 + j2]);
        float2 ev = e2[v * 16 + j2];
        float l0 = fminf(fmaxf(o0, -10.0f), 10.0f);
        float l1 = fminf(fmaxf(o1, -10.0f), 10.0f);
        half2v zw;
        zw.x = (_Float16)(val0 + ev.x * expf(l0));
        zw.y = (_Float16)(val1 + ev.y * expf(l1));
        z2[v * 16 + j2] = zw;
    } else {
        float2v lv; lv.x = val0; lv.y = val1;
        __builtin_nontemporal_store(lv, &ls2[v * 16 + (j2 - 16)]);
    }
}

// adj_pred[e] = sigmoid(<z[src], z[dst]>); z fp16 (row = 64 B = 1 line),
// 4 lanes per edge, 16 B loads
__global__ __launch_bounds__(256) void k_decode(const _Float16* __restrict__ zh,
                                                const int* __restrict__ src,
                                                const int* __restrict__ dst,
                                                float* __restrict__ out) {
    long t = (long)blockIdx.x * 256 + threadIdx.x;
    long e = t >> 2; int l = (int)(t & 3);
    if (e >= NE) return;
    int s = src[e], d = dst[e];
    const half8v* z8 = (const half8v*)zh;
    half8v a = z8[s * 4 + l];
    half8v b = z8[d * 4 + l];
    float p = 0.f;
#pragma unroll
    for (int i = 0; i < 8; ++i) p += (float)a[i] * (float)b[i];
    p += __shfl_xor(p, 1);
    p += __shfl_xor(p, 2);
    if (l == 0) out[e] = 1.0f / (1.0f + expf(-p));
}

extern "C" void kernel_launch(void* const* d_in, const int* in_sizes, int n_in,
                              void* d_out, int out_size, void* d_ws, size_t ws_size,
                              hipStream_t stream) {
    const float* x   = (const float*)d_in[0];
    const int*   ei  = (const int*)d_in[1];
    const float* eps = (const float*)d_in[2];
    const float* W1  = (const float*)d_in[3];
    const float* b1  = (const float*)d_in[4];
    const float* Wmu = (const float*)d_in[5];
    const float* bmu = (const float*)d_in[6];
    const float* Wls = (const float*)d_in[7];
    const float* bls = (const float*)d_in[8];
    const int* src = ei;        // edge_index[0]
    const int* dst = ei + NE;   // edge_index[1]

    float* out = (float*)d_out;
    float* adj = out;                       // [E]
    float* mu  = out + NE;                  // [N,32]
    float* ls  = mu + (long)NN * 32;        // [N,32]

    // workspace layout (all block byte sizes multiples of 16; z 64B-aligned)
    float* dis      = (float*)d_ws;              // NN
    int*   row_ptr  = (int*)(dis + NN);          // 100004
    int*   bucket_base = row_ptr + 100004;       // NB_BKT+1 -> pad 784
    int*   counts   = bucket_base + 784;         // NT*NB_BKT = 76636 -> pad 76640
    int*   ebuf     = counts + 76640;            // NE
    int*   csr_src  = ebuf + NE;                 // NE
    _Float16* t     = (_Float16*)(csr_src + NE); // NN*64 fp16 (t1' then t2')
    float* h        = (float*)(t + (long)NN * 64);         // NN*64 f32
    _Float16* zh    = (_Float16*)(h + (long)NN * 64 + 12); // NN*32 fp16, 64B-aligned

    const int B = 256;

    // CSR + deg/dis build — zero global atomics
    k_cnt  <<<NT, B, 0, stream>>>(dst, counts);
    k_bscan<<<1, 1024, 0, stream>>>(counts, bucket_base);
    k_offs <<<(NB_BKT + B - 1) / B, B, 0, stream>>>(bucket_base, counts);
    k_place<<<NT, B, 0, stream>>>(src, dst, counts, ebuf);
    k_build<<<NB_BKT, B, 0, stream>>>(bucket_base, ebuf, csr_src, row_ptr, dis);

    // layer 1
    k_gemm1<<<NN / 16, B, 0, stream>>>(x, W1, dis, t);
    k_agg1 <<<NN / 8, B, 0, stream>>>((const half2v*)t, row_ptr, csr_src, dis, b1, h);

    // layer 2
    k_gemm2<<<NN / 16, B, 0, stream>>>(h, Wmu, Wls, dis, t);
    k_agg2 <<<NN / 8, B, 0, stream>>>((const half2v*)t, row_ptr, csr_src, dis,
                                      bmu, bls, eps, mu, ls, zh);

    // decode
    k_decode<<<(int)(((long)NE * 4 + B - 1) / B), B, 0, stream>>>(zh, src, dst, adj);
}